// Round 10
// baseline (325.383 us; speedup 1.0000x reference)
//
#include <hip/hip_runtime.h>
#include <float.h>

typedef __bf16 bf16x8 __attribute__((ext_vector_type(8)));
typedef float f32x4 __attribute__((ext_vector_type(4)));
typedef unsigned short ushort8 __attribute__((ext_vector_type(8)));
typedef _Float16 h8 __attribute__((ext_vector_type(8)));

__device__ inline unsigned short f2bh(float f) {
    unsigned int u = __float_as_uint(f);
    return (unsigned short)((u + 0x7FFFu + ((u >> 16) & 1u)) >> 16);
}
__device__ inline float bh2f(unsigned short h) {
    return __uint_as_float((unsigned int)h << 16);
}
__device__ inline h8 h8max(h8 a, h8 b) {
    h8 r;
    #pragma unroll
    for (int i = 0; i < 8; ++i) r[i] = a[i] > b[i] ? a[i] : b[i];
    return r;
}
__device__ inline h8 h8fill(_Float16 v) {
    h8 r;
    #pragma unroll
    for (int i = 0; i < 8; ++i) r[i] = v;
    return r;
}

// ---------------- fp32 -> fp16 convert (+ zero cnt for the histogram) ----------------

__global__ void cvt16_kernel(const float* __restrict__ xin, _Float16* __restrict__ x16,
                             int total8, int* __restrict__ cnt, int N) {
    int i = blockIdx.x * blockDim.x + threadIdx.x;
    if (i < N) cnt[i] = 0;
    if (i >= total8) return;
    const float4* p = reinterpret_cast<const float4*>(xin + (size_t)i * 8);
    float4 a = p[0], b = p[1];
    h8 o;
    o[0] = (_Float16)a.x; o[1] = (_Float16)a.y; o[2] = (_Float16)a.z; o[3] = (_Float16)a.w;
    o[4] = (_Float16)b.x; o[5] = (_Float16)b.y; o[6] = (_Float16)b.z; o[7] = (_Float16)b.w;
    *reinterpret_cast<h8*>(x16 + (size_t)i * 8) = o;
}

// ---------------- CSR build: hist + scan + counting-sort partition ----------------

__global__ void hist_kernel(const int* __restrict__ dst, int E, int* __restrict__ cnt) {
    int e = blockIdx.x * blockDim.x + threadIdx.x;
    if (e < E) atomicAdd(&cnt[dst[e]], 1);
}

__global__ __launch_bounds__(256) void bsum_kernel(const int* __restrict__ cnt, int N,
                                                   int* __restrict__ bsum) {
    __shared__ int red[256];
    int t = threadIdx.x;
    int i = blockIdx.x * 256 + t;
    red[t] = (i < N) ? cnt[i] : 0;
    __syncthreads();
    for (int off = 128; off > 0; off >>= 1) {
        if (t < off) red[t] += red[t + off];
        __syncthreads();
    }
    if (t == 0) bsum[blockIdx.x] = red[0];
}

// Each block redundantly scans the (<=256) block sums, then scans its own 256
// counts; writes row_start (incl. row_start[N]=E), bucket cursors, zeroes pooled.
__global__ __launch_bounds__(256) void scan_apply_kernel(const int* __restrict__ cnt, int N,
                                                         const int* __restrict__ bsum, int nb,
                                                         int* __restrict__ row_start,
                                                         int* __restrict__ bcur,
                                                         unsigned int* __restrict__ pooled) {
    __shared__ int sb[256];
    __shared__ int s[256];
    int t = threadIdx.x;
    if (blockIdx.x == 0)
        for (int k = t; k < 64 * 128; k += 256) pooled[k] = 0u;
    sb[t] = (t < nb) ? bsum[t] : 0;
    int i = blockIdx.x * 256 + t;
    int v = (i < N) ? cnt[i] : 0;
    s[t] = v;
    __syncthreads();
    for (int off = 1; off < 256; off <<= 1) {
        int u0 = (t >= off) ? sb[t - off] : 0;
        int u1 = (t >= off) ? s[t - off] : 0;
        __syncthreads();
        sb[t] += u0;
        s[t] += u1;
        __syncthreads();
    }
    int base = (blockIdx.x == 0) ? 0 : sb[blockIdx.x - 1];
    int excl = base + s[t] - v;
    if (i < N) {
        row_start[i] = excl;
        if ((i & 63) == 0) bcur[i >> 6] = excl;   // bucket = 64 nodes
        if (i == N - 1) row_start[N] = excl + v;  // = E
    }
}

// Pass A (counting-sort style): LDS histogram per block, one global atomicAdd
// per non-empty bucket per block, then LDS-cursor ranked packed writes.
#define EPB 8192

__global__ __launch_bounds__(256) void partA_kernel(const int* __restrict__ src,
                                                    const int* __restrict__ dst, int E,
                                                    int nbkt, int* __restrict__ bcur,
                                                    unsigned int* __restrict__ pk) {
    __shared__ int lh[1024];
    __shared__ int lbase[1024];
    int t = threadIdx.x;
    int e0 = blockIdx.x * EPB;
    int e1 = e0 + EPB; if (e1 > E) e1 = E;
    for (int b = t; b < nbkt; b += 256) lh[b] = 0;
    __syncthreads();
    for (int e = e0 + t; e < e1; e += 256)
        atomicAdd(&lh[dst[e] >> 6], 1);
    __syncthreads();
    for (int b = t; b < nbkt; b += 256) {
        int c = lh[b];
        lbase[b] = (c > 0) ? atomicAdd(&bcur[b], c) : 0;
        lh[b] = 0;
    }
    __syncthreads();
    for (int e = e0 + t; e < e1; e += 256) {
        int d = dst[e];
        int b = d >> 6;
        int r = atomicAdd(&lh[b], 1);
        pk[lbase[b] + r] = ((unsigned int)src[e] << 6) | (unsigned int)(d & 63);
    }
}

// Pass B: one block per bucket; LDS cursors rank edges within each node.
__global__ __launch_bounds__(256) void partB_kernel(const unsigned int* __restrict__ pk,
                                                    const int* __restrict__ row_start,
                                                    int N, int E, int* __restrict__ col) {
    __shared__ int lrs[64];
    __shared__ int lcur[64];
    int b = blockIdx.x;
    int base = b * 64;
    int t = threadIdx.x;
    if (t < 64) {
        int node = base + t;
        lrs[t] = (node < N) ? row_start[node] : E;
        lcur[t] = 0;
    }
    __syncthreads();
    int lo = row_start[base];
    int nxt = base + 64; if (nxt > N) nxt = N;
    int hi = row_start[nxt];
    for (int i = lo + t; i < hi; i += 256) {
        unsigned int w = pk[i];
        int dl = w & 63u;
        int s = (int)(w >> 6);
        int r = atomicAdd(&lcur[dl], 1);
        col[lrs[dl] + r] = s;
    }
}

// ---------------- max aggregation (fp16): 16 lanes/node, h8, 8-way unrolled ----------------
// 16B/lane loads halve the per-edge instruction count; 8 independent
// accumulators give 32 outstanding gathers per wave; N*16 threads for TLP.

__global__ __launch_bounds__(256) void agg_kernel(const _Float16* __restrict__ x16,
                                                  const int* __restrict__ row_start,
                                                  const int* __restrict__ col,
                                                  _Float16* __restrict__ agg16, int N) {
    int gid = blockIdx.x * blockDim.x + threadIdx.x;
    int node = gid >> 4;
    int l16 = gid & 15;
    if (node >= N) return;
    int beg = row_start[node];
    int deg = row_start[node + 1] - beg;
    const _Float16* xb = x16 + (size_t)l16 * 8;
    const _Float16 NEG = (_Float16)(-65504.0f);
    h8 a0 = h8fill(NEG), a1 = a0, a2 = a0, a3 = a0, a4 = a0, a5 = a0, a6 = a0, a7 = a0;
    int j = 0;
    for (; j + 8 <= deg; j += 8) {
        int s0 = col[beg + j];
        int s1 = col[beg + j + 1];
        int s2 = col[beg + j + 2];
        int s3 = col[beg + j + 3];
        int s4 = col[beg + j + 4];
        int s5 = col[beg + j + 5];
        int s6 = col[beg + j + 6];
        int s7 = col[beg + j + 7];
        a0 = h8max(a0, *reinterpret_cast<const h8*>(xb + (size_t)s0 * 128));
        a1 = h8max(a1, *reinterpret_cast<const h8*>(xb + (size_t)s1 * 128));
        a2 = h8max(a2, *reinterpret_cast<const h8*>(xb + (size_t)s2 * 128));
        a3 = h8max(a3, *reinterpret_cast<const h8*>(xb + (size_t)s3 * 128));
        a4 = h8max(a4, *reinterpret_cast<const h8*>(xb + (size_t)s4 * 128));
        a5 = h8max(a5, *reinterpret_cast<const h8*>(xb + (size_t)s5 * 128));
        a6 = h8max(a6, *reinterpret_cast<const h8*>(xb + (size_t)s6 * 128));
        a7 = h8max(a7, *reinterpret_cast<const h8*>(xb + (size_t)s7 * 128));
    }
    for (; j < deg; ++j) {
        int s0 = col[beg + j];
        a0 = h8max(a0, *reinterpret_cast<const h8*>(xb + (size_t)s0 * 128));
    }
    a0 = h8max(h8max(h8max(a0, a1), h8max(a2, a3)),
               h8max(h8max(a4, a5), h8max(a6, a7)));
    if (deg == 0) a0 = h8fill((_Float16)0.f);
    *reinterpret_cast<h8*>(&agg16[(size_t)node * 128 + l16 * 8]) = a0;
}

// ---------------- W prep: split fp32 W into bf16 hi/lo, fragment-ordered ----------------
// dest layout per layer: [phase(2)][kgroup(16)][col(128)][j(8)].

__global__ void wprep_kernel(const float* __restrict__ Wn, const float* __restrict__ Wsf,
                             int total, unsigned short* __restrict__ Wfh,
                             unsigned short* __restrict__ Wfl) {
    int idx = blockIdx.x * blockDim.x + threadIdx.x;
    if (idx >= total) return;
    int c = idx & 127;
    int k = (idx >> 7) & 127;
    int p = (idx >> 14) & 1;
    int l = idx >> 15;
    const float* W = p ? Wsf : Wn;
    float v = W[(size_t)l * 16384 + k * 128 + c];
    unsigned short hi = f2bh(v);
    unsigned short lo = f2bh(v - bh2f(hi));
    size_t d = ((((size_t)l * 2 + p) * 16 + (k >> 3)) * 128 + c) * 8 + (k & 7);
    Wfh[d] = hi;
    Wfl[d] = lo;
}

// ---------------- layer GEMM via MFMA: relu([agg|x]@[Wn;Ws] + b) ----------------
// 16 rows x 64 cols per wave -> 6250 waves for latency hiding.
// 3-term split-bf16 (Ah@Wh + Al@Wh + Ah@Wl); fp16 A splits exactly into bf16 hi+lo.

__global__ __launch_bounds__(256) void layer_mfma(
    const _Float16* __restrict__ agg16, const _Float16* __restrict__ xin16,
    const unsigned short* __restrict__ Wfh, const unsigned short* __restrict__ Wfl,
    const float* __restrict__ bias, _Float16* __restrict__ xout16, int N)
{
    const int lane = threadIdx.x & 63;
    const int wid  = threadIdx.x >> 6;   // 0..3
    const int l15  = lane & 15;
    const int lg   = lane >> 4;          // 0..3
    const int ch   = wid & 1;            // col half
    const int rg   = wid >> 1;           // row group
    const int row0 = blockIdx.x * 32 + rg * 16;

    f32x4 acc[4];
    #pragma unroll
    for (int nt = 0; nt < 4; ++nt) { f32x4 z = {0.f, 0.f, 0.f, 0.f}; acc[nt] = z; }

    int rc = row0 + l15; if (rc > N - 1) rc = N - 1;

    #pragma unroll
    for (int p = 0; p < 2; ++p) {
        const _Float16* A = p ? xin16 : agg16;
        const _Float16* a = A + (size_t)rc * 128 + lg * 8;
        const unsigned short* wh0 = Wfh + p * 16384 + (size_t)(ch * 64 + l15) * 8 + lg * 1024;
        const unsigned short* wl0 = Wfl + p * 16384 + (size_t)(ch * 64 + l15) * 8 + lg * 1024;
        #pragma unroll
        for (int ks = 0; ks < 4; ++ks) {
            h8 av = *reinterpret_cast<const h8*>(a + ks * 32);
            ushort8 hh, ll;
            #pragma unroll
            for (int j = 0; j < 8; ++j) {
                float f = (float)av[j];
                unsigned short hi = f2bh(f);
                float r = f - bh2f(hi);          // exactly representable in bf16
                hh[j] = hi;
                ll[j] = (unsigned short)(__float_as_uint(r) >> 16);
            }
            bf16x8 ah = __builtin_bit_cast(bf16x8, hh);
            bf16x8 al = __builtin_bit_cast(bf16x8, ll);
            const unsigned short* whk = wh0 + ks * 4096;
            const unsigned short* wlk = wl0 + ks * 4096;
            #pragma unroll
            for (int nt = 0; nt < 4; ++nt) {
                bf16x8 bh = *reinterpret_cast<const bf16x8*>(whk + nt * 128);
                bf16x8 bl = *reinterpret_cast<const bf16x8*>(wlk + nt * 128);
                acc[nt] = __builtin_amdgcn_mfma_f32_16x16x32_bf16(ah, bh, acc[nt], 0, 0, 0);
                acc[nt] = __builtin_amdgcn_mfma_f32_16x16x32_bf16(al, bh, acc[nt], 0, 0, 0);
                acc[nt] = __builtin_amdgcn_mfma_f32_16x16x32_bf16(ah, bl, acc[nt], 0, 0, 0);
            }
        }
    }

    #pragma unroll
    for (int nt = 0; nt < 4; ++nt) {
        int colb = ch * 64 + nt * 16 + l15;
        float bv = bias[colb];
        #pragma unroll
        for (int rr = 0; rr < 4; ++rr) {
            int row = row0 + lg * 4 + rr;
            if (row < N) {
                float o = fmaxf(acc[nt][rr] + bv, 0.f);
                xout16[(size_t)row * 128 + colb] = (_Float16)o;
            }
        }
    }
}

// ---------------- global max pool per graph: chunked + atomicMax ----------------

#define POOL_CHUNK 128

__global__ __launch_bounds__(128) void pool_kernel(const _Float16* __restrict__ x16,
                                                   const int* __restrict__ batch,
                                                   int N,
                                                   unsigned int* __restrict__ pooled) {
    int f = threadIdx.x;
    int n0 = blockIdx.x * POOL_CHUNK;
    if (n0 >= N) return;
    int n1 = n0 + POOL_CHUNK; if (n1 > N) n1 = N;
    int g = batch[n0];
    float m = 0.f;
    for (int n = n0; n < n1; ++n) {
        int bg = batch[n];
        if (bg != g) {
            atomicMax(&pooled[g * 128 + f], __float_as_uint(m));
            m = 0.f; g = bg;
        }
        m = fmaxf(m, (float)x16[(size_t)n * 128 + f]);
    }
    atomicMax(&pooled[g * 128 + f], __float_as_uint(m));
}

// ---------------- head ----------------

__global__ __launch_bounds__(256) void head_kernel(
    const float* __restrict__ pooled,
    const float* __restrict__ linW, const float* __restrict__ linb,
    const float* __restrict__ outW, const float* __restrict__ outb,
    float* __restrict__ out)
{
    __shared__ float pl[128];
    __shared__ float hrow[256];
    int g = blockIdx.x, t = threadIdx.x;
    if (t < 128) pl[t] = pooled[g * 128 + t];
    __syncthreads();
    float acc = linb[t];
    for (int k = 0; k < 128; ++k) acc += pl[k] * linW[k * 256 + t];
    hrow[t] = acc;
    __syncthreads();
    if (t < 10) {
        float o = outb[t];
        for (int k = 0; k < 256; ++k) o += hrow[k] * outW[k * 10 + t];
        out[g * 10 + t] = o;
    }
}

// ---------------- launch ----------------

static inline size_t align_up(size_t v, size_t a) { return (v + a - 1) & ~(a - 1); }

extern "C" void kernel_launch(void* const* d_in, const int* in_sizes, int n_in,
                              void* d_out, int out_size, void* d_ws, size_t ws_size,
                              hipStream_t stream) {
    const float* x      = (const float*)d_in[0];
    const int*   ei     = (const int*)d_in[1];
    const int*   batch  = (const int*)d_in[2];
    const float* WsSelf = (const float*)d_in[3];
    const float* WsNei  = (const float*)d_in[4];
    const float* bsAll  = (const float*)d_in[5];
    const float* linW   = (const float*)d_in[6];
    const float* linb   = (const float*)d_in[7];
    const float* outW   = (const float*)d_in[8];
    const float* outb   = (const float*)d_in[9];

    const int N = in_sizes[0] / 128;
    const int E = in_sizes[1] / 2;
    const int L = in_sizes[3] / (128 * 128);
    const int* src = ei;
    const int* dst = ei + E;
    const int nb2 = (N + 63) / 64;     // 64-node buckets (<=1024 assumed)

    // workspace carve
    char* w = (char*)d_ws;
    int* cnt       = (int*)w;  w += align_up((size_t)N * 4, 256);
    int* row_start = (int*)w;  w += align_up((size_t)(N + 1) * 4, 256);
    int* bcur      = (int*)w;  w += align_up((size_t)nb2 * 4, 256);
    int* bsum      = (int*)w;  w += align_up(256 * 4, 256);
    unsigned int* pk = (unsigned int*)w; w += align_up((size_t)E * 4, 256);
    int* col       = (int*)w;  w += align_up((size_t)E * 4, 256);
    _Float16* agg16 = (_Float16*)w; w += align_up((size_t)N * 128 * 2, 256);
    _Float16* x16in = (_Float16*)w; w += align_up((size_t)N * 128 * 2, 256);
    _Float16* xa16  = (_Float16*)w; w += align_up((size_t)N * 128 * 2, 256);
    _Float16* xb16  = (_Float16*)w; w += align_up((size_t)N * 128 * 2, 256);
    float* pooled  = (float*)w; w += align_up((size_t)64 * 128 * 4, 256);
    unsigned short* Wfh = (unsigned short*)w; w += align_up((size_t)L * 2 * 16384 * 2, 256);
    unsigned short* Wfl = (unsigned short*)w; w += align_up((size_t)L * 2 * 16384 * 2, 256);
    (void)ws_size;

    cvt16_kernel<<<(N * 16 + 255) / 256, 256, 0, stream>>>(x, x16in, N * 16, cnt, N);

    const int wtotal = L * 2 * 128 * 128;
    wprep_kernel<<<(wtotal + 255) / 256, 256, 0, stream>>>(WsNei, WsSelf, wtotal, Wfh, Wfl);

    const int nb = (N + 255) / 256;
    hist_kernel<<<(E + 255) / 256, 256, 0, stream>>>(dst, E, cnt);
    bsum_kernel<<<nb, 256, 0, stream>>>(cnt, N, bsum);
    scan_apply_kernel<<<nb, 256, 0, stream>>>(cnt, N, bsum, nb, row_start, bcur,
                                              (unsigned int*)pooled);
    partA_kernel<<<(E + EPB - 1) / EPB, 256, 0, stream>>>(src, dst, E, nb2, bcur, pk);
    partB_kernel<<<nb2, 256, 0, stream>>>(pk, row_start, N, E, col);

    const _Float16* xin16 = x16in;
    _Float16* bufs[2] = { xa16, xb16 };
    for (int l = 0; l < L; ++l) {
        agg_kernel<<<(N * 16 + 255) / 256, 256, 0, stream>>>(xin16, row_start, col, agg16, N);
        layer_mfma<<<(N + 31) / 32, 256, 0, stream>>>(
            agg16, xin16,
            Wfh + (size_t)l * 2 * 16384, Wfl + (size_t)l * 2 * 16384,
            bsAll + (size_t)l * 128, bufs[l & 1], N);
        xin16 = bufs[l & 1];
    }

    pool_kernel<<<(N + POOL_CHUNK - 1) / POOL_CHUNK, 128, 0, stream>>>(
        xin16, batch, N, (unsigned int*)pooled);
    head_kernel<<<64, 256, 0, stream>>>(pooled, linW, linb, outW, outb, (float*)d_out);
}

// Round 11
// 306.018 us; speedup vs baseline: 1.0633x; 1.0633x over previous
//
#include <hip/hip_runtime.h>
#include <float.h>

typedef __bf16 bf16x8 __attribute__((ext_vector_type(8)));
typedef float f32x4 __attribute__((ext_vector_type(4)));
typedef unsigned short ushort8 __attribute__((ext_vector_type(8)));
typedef _Float16 h8 __attribute__((ext_vector_type(8)));
typedef _Float16 h4 __attribute__((ext_vector_type(4)));

__device__ inline unsigned short f2bh(float f) {
    unsigned int u = __float_as_uint(f);
    return (unsigned short)((u + 0x7FFFu + ((u >> 16) & 1u)) >> 16);
}
__device__ inline float bh2f(unsigned short h) {
    return __uint_as_float((unsigned int)h << 16);
}
__device__ inline h4 h4max(h4 a, h4 b) {
    h4 r;
    r[0] = a[0] > b[0] ? a[0] : b[0];
    r[1] = a[1] > b[1] ? a[1] : b[1];
    r[2] = a[2] > b[2] ? a[2] : b[2];
    r[3] = a[3] > b[3] ? a[3] : b[3];
    return r;
}

// ---------------- fp32 -> fp16 convert (+ zero cnt for the histogram) ----------------

__global__ void cvt16_kernel(const float* __restrict__ xin, _Float16* __restrict__ x16,
                             int total8, int* __restrict__ cnt, int N) {
    int i = blockIdx.x * blockDim.x + threadIdx.x;
    if (i < N) cnt[i] = 0;
    if (i >= total8) return;
    const float4* p = reinterpret_cast<const float4*>(xin + (size_t)i * 8);
    float4 a = p[0], b = p[1];
    h8 o;
    o[0] = (_Float16)a.x; o[1] = (_Float16)a.y; o[2] = (_Float16)a.z; o[3] = (_Float16)a.w;
    o[4] = (_Float16)b.x; o[5] = (_Float16)b.y; o[6] = (_Float16)b.z; o[7] = (_Float16)b.w;
    *reinterpret_cast<h8*>(x16 + (size_t)i * 8) = o;
}

// ---------------- CSR build: hist + scan + counting-sort partition ----------------

__global__ void hist_kernel(const int* __restrict__ dst, int E, int* __restrict__ cnt) {
    int e = blockIdx.x * blockDim.x + threadIdx.x;
    if (e < E) atomicAdd(&cnt[dst[e]], 1);
}

__global__ __launch_bounds__(256) void bsum_kernel(const int* __restrict__ cnt, int N,
                                                   int* __restrict__ bsum) {
    __shared__ int red[256];
    int t = threadIdx.x;
    int i = blockIdx.x * 256 + t;
    red[t] = (i < N) ? cnt[i] : 0;
    __syncthreads();
    for (int off = 128; off > 0; off >>= 1) {
        if (t < off) red[t] += red[t + off];
        __syncthreads();
    }
    if (t == 0) bsum[blockIdx.x] = red[0];
}

// Each block redundantly scans the (<=256) block sums, then scans its own 256
// counts; writes row_start (incl. row_start[N]=E), bucket cursors, zeroes pooled.
__global__ __launch_bounds__(256) void scan_apply_kernel(const int* __restrict__ cnt, int N,
                                                         const int* __restrict__ bsum, int nb,
                                                         int* __restrict__ row_start,
                                                         int* __restrict__ bcur,
                                                         unsigned int* __restrict__ pooled) {
    __shared__ int sb[256];
    __shared__ int s[256];
    int t = threadIdx.x;
    if (blockIdx.x == 0)
        for (int k = t; k < 64 * 128; k += 256) pooled[k] = 0u;
    sb[t] = (t < nb) ? bsum[t] : 0;
    int i = blockIdx.x * 256 + t;
    int v = (i < N) ? cnt[i] : 0;
    s[t] = v;
    __syncthreads();
    for (int off = 1; off < 256; off <<= 1) {
        int u0 = (t >= off) ? sb[t - off] : 0;
        int u1 = (t >= off) ? s[t - off] : 0;
        __syncthreads();
        sb[t] += u0;
        s[t] += u1;
        __syncthreads();
    }
    int base = (blockIdx.x == 0) ? 0 : sb[blockIdx.x - 1];
    int excl = base + s[t] - v;
    if (i < N) {
        row_start[i] = excl;
        if ((i & 63) == 0) bcur[i >> 6] = excl;   // bucket = 64 nodes
        if (i == N - 1) row_start[N] = excl + v;  // = E
    }
}

// Pass A (counting-sort style): LDS histogram per block, one global atomicAdd
// per non-empty bucket per block, then LDS-cursor ranked packed writes.
#define EPB 8192

__global__ __launch_bounds__(256) void partA_kernel(const int* __restrict__ src,
                                                    const int* __restrict__ dst, int E,
                                                    int nbkt, int* __restrict__ bcur,
                                                    unsigned int* __restrict__ pk) {
    __shared__ int lh[1024];
    __shared__ int lbase[1024];
    int t = threadIdx.x;
    int e0 = blockIdx.x * EPB;
    int e1 = e0 + EPB; if (e1 > E) e1 = E;
    for (int b = t; b < nbkt; b += 256) lh[b] = 0;
    __syncthreads();
    for (int e = e0 + t; e < e1; e += 256)
        atomicAdd(&lh[dst[e] >> 6], 1);
    __syncthreads();
    for (int b = t; b < nbkt; b += 256) {
        int c = lh[b];
        lbase[b] = (c > 0) ? atomicAdd(&bcur[b], c) : 0;
        lh[b] = 0;
    }
    __syncthreads();
    for (int e = e0 + t; e < e1; e += 256) {
        int d = dst[e];
        int b = d >> 6;
        int r = atomicAdd(&lh[b], 1);
        pk[lbase[b] + r] = ((unsigned int)src[e] << 6) | (unsigned int)(d & 63);
    }
}

// Pass B: one block per bucket; LDS cursors rank edges within each node.
__global__ __launch_bounds__(256) void partB_kernel(const unsigned int* __restrict__ pk,
                                                    const int* __restrict__ row_start,
                                                    int N, int E, int* __restrict__ col) {
    __shared__ int lrs[64];
    __shared__ int lcur[64];
    int b = blockIdx.x;
    int base = b * 64;
    int t = threadIdx.x;
    if (t < 64) {
        int node = base + t;
        lrs[t] = (node < N) ? row_start[node] : E;
        lcur[t] = 0;
    }
    __syncthreads();
    int lo = row_start[base];
    int nxt = base + 64; if (nxt > N) nxt = N;
    int hi = row_start[nxt];
    for (int i = lo + t; i < hi; i += 256) {
        unsigned int w = pk[i];
        int dl = w & 63u;
        int s = (int)(w >> 6);
        int r = atomicAdd(&lcur[dl], 1);
        col[lrs[dl] + r] = s;
    }
}

// ---------------- max aggregation (fp16): 32 lanes/node, h4, 4-way unrolled ----------------
// Proven-best shape (R5/R8): 2 nodes/wave, ~12 VGPR -> full occupancy, 25k waves;
// 4 independent accumulators break the col->gather->max dependency chain.

__global__ __launch_bounds__(256) void agg_kernel(const _Float16* __restrict__ x16,
                                                  const int* __restrict__ row_start,
                                                  const int* __restrict__ col,
                                                  _Float16* __restrict__ agg16, int N) {
    int gid = blockIdx.x * blockDim.x + threadIdx.x;
    int node = gid >> 5;
    int lane = gid & 31;
    if (node >= N) return;
    int beg = row_start[node];
    int deg = row_start[node + 1] - beg;
    const _Float16 NEG = (_Float16)(-65504.0f);
    h4 a0, a1, a2, a3;
    a0[0] = NEG; a0[1] = NEG; a0[2] = NEG; a0[3] = NEG;
    a1 = a0; a2 = a0; a3 = a0;
    int j = 0;
    for (; j + 4 <= deg; j += 4) {
        int s0 = col[beg + j];
        int s1 = col[beg + j + 1];
        int s2 = col[beg + j + 2];
        int s3 = col[beg + j + 3];
        h4 v0 = *reinterpret_cast<const h4*>(&x16[(size_t)s0 * 128 + lane * 4]);
        h4 v1 = *reinterpret_cast<const h4*>(&x16[(size_t)s1 * 128 + lane * 4]);
        h4 v2 = *reinterpret_cast<const h4*>(&x16[(size_t)s2 * 128 + lane * 4]);
        h4 v3 = *reinterpret_cast<const h4*>(&x16[(size_t)s3 * 128 + lane * 4]);
        a0 = h4max(a0, v0);
        a1 = h4max(a1, v1);
        a2 = h4max(a2, v2);
        a3 = h4max(a3, v3);
    }
    for (; j < deg; ++j) {
        int s0 = col[beg + j];
        h4 v0 = *reinterpret_cast<const h4*>(&x16[(size_t)s0 * 128 + lane * 4]);
        a0 = h4max(a0, v0);
    }
    a0 = h4max(h4max(a0, a1), h4max(a2, a3));
    if (deg == 0) { a0[0] = (_Float16)0.f; a0[1] = (_Float16)0.f; a0[2] = (_Float16)0.f; a0[3] = (_Float16)0.f; }
    *reinterpret_cast<h4*>(&agg16[(size_t)node * 128 + lane * 4]) = a0;
}

// ---------------- W prep: split fp32 W into bf16 hi/lo, fragment-ordered ----------------
// dest layout per layer: [phase(2)][kgroup(16)][col(128)][j(8)].

__global__ void wprep_kernel(const float* __restrict__ Wn, const float* __restrict__ Wsf,
                             int total, unsigned short* __restrict__ Wfh,
                             unsigned short* __restrict__ Wfl) {
    int idx = blockIdx.x * blockDim.x + threadIdx.x;
    if (idx >= total) return;
    int c = idx & 127;
    int k = (idx >> 7) & 127;
    int p = (idx >> 14) & 1;
    int l = idx >> 15;
    const float* W = p ? Wsf : Wn;
    float v = W[(size_t)l * 16384 + k * 128 + c];
    unsigned short hi = f2bh(v);
    unsigned short lo = f2bh(v - bh2f(hi));
    size_t d = ((((size_t)l * 2 + p) * 16 + (k >> 3)) * 128 + c) * 8 + (k & 7);
    Wfh[d] = hi;
    Wfl[d] = lo;
}

// ---------------- layer GEMM via MFMA: relu([agg|x]@[Wn;Ws] + b) ----------------
// 16 rows x 64 cols per wave -> 6250 waves for latency hiding.
// 3-term split-bf16 (Ah@Wh + Al@Wh + Ah@Wl); fp16 A splits exactly into bf16 hi+lo.

__global__ __launch_bounds__(256) void layer_mfma(
    const _Float16* __restrict__ agg16, const _Float16* __restrict__ xin16,
    const unsigned short* __restrict__ Wfh, const unsigned short* __restrict__ Wfl,
    const float* __restrict__ bias, _Float16* __restrict__ xout16, int N)
{
    const int lane = threadIdx.x & 63;
    const int wid  = threadIdx.x >> 6;   // 0..3
    const int l15  = lane & 15;
    const int lg   = lane >> 4;          // 0..3
    const int ch   = wid & 1;            // col half
    const int rg   = wid >> 1;           // row group
    const int row0 = blockIdx.x * 32 + rg * 16;

    f32x4 acc[4];
    #pragma unroll
    for (int nt = 0; nt < 4; ++nt) { f32x4 z = {0.f, 0.f, 0.f, 0.f}; acc[nt] = z; }

    int rc = row0 + l15; if (rc > N - 1) rc = N - 1;

    #pragma unroll
    for (int p = 0; p < 2; ++p) {
        const _Float16* A = p ? xin16 : agg16;
        const _Float16* a = A + (size_t)rc * 128 + lg * 8;
        const unsigned short* wh0 = Wfh + p * 16384 + (size_t)(ch * 64 + l15) * 8 + lg * 1024;
        const unsigned short* wl0 = Wfl + p * 16384 + (size_t)(ch * 64 + l15) * 8 + lg * 1024;
        #pragma unroll
        for (int ks = 0; ks < 4; ++ks) {
            h8 av = *reinterpret_cast<const h8*>(a + ks * 32);
            ushort8 hh, ll;
            #pragma unroll
            for (int j = 0; j < 8; ++j) {
                float f = (float)av[j];
                unsigned short hi = f2bh(f);
                float r = f - bh2f(hi);          // exactly representable in bf16
                hh[j] = hi;
                ll[j] = (unsigned short)(__float_as_uint(r) >> 16);
            }
            bf16x8 ah = __builtin_bit_cast(bf16x8, hh);
            bf16x8 al = __builtin_bit_cast(bf16x8, ll);
            const unsigned short* whk = wh0 + ks * 4096;
            const unsigned short* wlk = wl0 + ks * 4096;
            #pragma unroll
            for (int nt = 0; nt < 4; ++nt) {
                bf16x8 bh = *reinterpret_cast<const bf16x8*>(whk + nt * 128);
                bf16x8 bl = *reinterpret_cast<const bf16x8*>(wlk + nt * 128);
                acc[nt] = __builtin_amdgcn_mfma_f32_16x16x32_bf16(ah, bh, acc[nt], 0, 0, 0);
                acc[nt] = __builtin_amdgcn_mfma_f32_16x16x32_bf16(al, bh, acc[nt], 0, 0, 0);
                acc[nt] = __builtin_amdgcn_mfma_f32_16x16x32_bf16(ah, bl, acc[nt], 0, 0, 0);
            }
        }
    }

    #pragma unroll
    for (int nt = 0; nt < 4; ++nt) {
        int colb = ch * 64 + nt * 16 + l15;
        float bv = bias[colb];
        #pragma unroll
        for (int rr = 0; rr < 4; ++rr) {
            int row = row0 + lg * 4 + rr;
            if (row < N) {
                float o = fmaxf(acc[nt][rr] + bv, 0.f);
                xout16[(size_t)row * 128 + colb] = (_Float16)o;
            }
        }
    }
}

// ---------------- global max pool per graph: chunked + atomicMax ----------------

#define POOL_CHUNK 128

__global__ __launch_bounds__(128) void pool_kernel(const _Float16* __restrict__ x16,
                                                   const int* __restrict__ batch,
                                                   int N,
                                                   unsigned int* __restrict__ pooled) {
    int f = threadIdx.x;
    int n0 = blockIdx.x * POOL_CHUNK;
    if (n0 >= N) return;
    int n1 = n0 + POOL_CHUNK; if (n1 > N) n1 = N;
    int g = batch[n0];
    float m = 0.f;
    for (int n = n0; n < n1; ++n) {
        int bg = batch[n];
        if (bg != g) {
            atomicMax(&pooled[g * 128 + f], __float_as_uint(m));
            m = 0.f; g = bg;
        }
        m = fmaxf(m, (float)x16[(size_t)n * 128 + f]);
    }
    atomicMax(&pooled[g * 128 + f], __float_as_uint(m));
}

// ---------------- head ----------------

__global__ __launch_bounds__(256) void head_kernel(
    const float* __restrict__ pooled,
    const float* __restrict__ linW, const float* __restrict__ linb,
    const float* __restrict__ outW, const float* __restrict__ outb,
    float* __restrict__ out)
{
    __shared__ float pl[128];
    __shared__ float hrow[256];
    int g = blockIdx.x, t = threadIdx.x;
    if (t < 128) pl[t] = pooled[g * 128 + t];
    __syncthreads();
    float acc = linb[t];
    for (int k = 0; k < 128; ++k) acc += pl[k] * linW[k * 256 + t];
    hrow[t] = acc;
    __syncthreads();
    if (t < 10) {
        float o = outb[t];
        for (int k = 0; k < 256; ++k) o += hrow[k] * outW[k * 10 + t];
        out[g * 10 + t] = o;
    }
}

// ---------------- launch ----------------

static inline size_t align_up(size_t v, size_t a) { return (v + a - 1) & ~(a - 1); }

extern "C" void kernel_launch(void* const* d_in, const int* in_sizes, int n_in,
                              void* d_out, int out_size, void* d_ws, size_t ws_size,
                              hipStream_t stream) {
    const float* x      = (const float*)d_in[0];
    const int*   ei     = (const int*)d_in[1];
    const int*   batch  = (const int*)d_in[2];
    const float* WsSelf = (const float*)d_in[3];
    const float* WsNei  = (const float*)d_in[4];
    const float* bsAll  = (const float*)d_in[5];
    const float* linW   = (const float*)d_in[6];
    const float* linb   = (const float*)d_in[7];
    const float* outW   = (const float*)d_in[8];
    const float* outb   = (const float*)d_in[9];

    const int N = in_sizes[0] / 128;
    const int E = in_sizes[1] / 2;
    const int L = in_sizes[3] / (128 * 128);
    const int* src = ei;
    const int* dst = ei + E;
    const int nb2 = (N + 63) / 64;     // 64-node buckets (<=1024 assumed)

    // workspace carve
    char* w = (char*)d_ws;
    int* cnt       = (int*)w;  w += align_up((size_t)N * 4, 256);
    int* row_start = (int*)w;  w += align_up((size_t)(N + 1) * 4, 256);
    int* bcur      = (int*)w;  w += align_up((size_t)nb2 * 4, 256);
    int* bsum      = (int*)w;  w += align_up(256 * 4, 256);
    unsigned int* pk = (unsigned int*)w; w += align_up((size_t)E * 4, 256);
    int* col       = (int*)w;  w += align_up((size_t)E * 4, 256);
    _Float16* agg16 = (_Float16*)w; w += align_up((size_t)N * 128 * 2, 256);
    _Float16* x16in = (_Float16*)w; w += align_up((size_t)N * 128 * 2, 256);
    _Float16* xa16  = (_Float16*)w; w += align_up((size_t)N * 128 * 2, 256);
    _Float16* xb16  = (_Float16*)w; w += align_up((size_t)N * 128 * 2, 256);
    float* pooled  = (float*)w; w += align_up((size_t)64 * 128 * 4, 256);
    unsigned short* Wfh = (unsigned short*)w; w += align_up((size_t)L * 2 * 16384 * 2, 256);
    unsigned short* Wfl = (unsigned short*)w; w += align_up((size_t)L * 2 * 16384 * 2, 256);
    (void)ws_size;

    cvt16_kernel<<<(N * 16 + 255) / 256, 256, 0, stream>>>(x, x16in, N * 16, cnt, N);

    const int wtotal = L * 2 * 128 * 128;
    wprep_kernel<<<(wtotal + 255) / 256, 256, 0, stream>>>(WsNei, WsSelf, wtotal, Wfh, Wfl);

    const int nb = (N + 255) / 256;
    hist_kernel<<<(E + 255) / 256, 256, 0, stream>>>(dst, E, cnt);
    bsum_kernel<<<nb, 256, 0, stream>>>(cnt, N, bsum);
    scan_apply_kernel<<<nb, 256, 0, stream>>>(cnt, N, bsum, nb, row_start, bcur,
                                              (unsigned int*)pooled);
    partA_kernel<<<(E + EPB - 1) / EPB, 256, 0, stream>>>(src, dst, E, nb2, bcur, pk);
    partB_kernel<<<nb2, 256, 0, stream>>>(pk, row_start, N, E, col);

    const _Float16* xin16 = x16in;
    _Float16* bufs[2] = { xa16, xb16 };
    for (int l = 0; l < L; ++l) {
        agg_kernel<<<(N * 32 + 255) / 256, 256, 0, stream>>>(xin16, row_start, col, agg16, N);
        layer_mfma<<<(N + 31) / 32, 256, 0, stream>>>(
            agg16, xin16,
            Wfh + (size_t)l * 2 * 16384, Wfl + (size_t)l * 2 * 16384,
            bsAll + (size_t)l * 128, bufs[l & 1], N);
        xin16 = bufs[l & 1];
    }

    pool_kernel<<<(N + POOL_CHUNK - 1) / POOL_CHUNK, 128, 0, stream>>>(
        xin16, batch, N, (unsigned int*)pooled);
    head_kernel<<<64, 256, 0, stream>>>(pooled, linW, linb, outW, outb, (float*)d_out);
}

// Round 12
// 296.403 us; speedup vs baseline: 1.0978x; 1.0324x over previous
//
#include <hip/hip_runtime.h>
#include <float.h>

typedef __bf16 bf16x8 __attribute__((ext_vector_type(8)));
typedef float f32x4 __attribute__((ext_vector_type(4)));
typedef unsigned short ushort8 __attribute__((ext_vector_type(8)));
typedef _Float16 h8 __attribute__((ext_vector_type(8)));
typedef _Float16 h4 __attribute__((ext_vector_type(4)));

__device__ inline unsigned short f2bh(float f) {
    unsigned int u = __float_as_uint(f);
    return (unsigned short)((u + 0x7FFFu + ((u >> 16) & 1u)) >> 16);
}
__device__ inline float bh2f(unsigned short h) {
    return __uint_as_float((unsigned int)h << 16);
}
__device__ inline h4 h4max(h4 a, h4 b) {
    h4 r;
    r[0] = a[0] > b[0] ? a[0] : b[0];
    r[1] = a[1] > b[1] ? a[1] : b[1];
    r[2] = a[2] > b[2] ? a[2] : b[2];
    r[3] = a[3] > b[3] ? a[3] : b[3];
    return r;
}

// ---------------- fp32 -> fp16 convert (+ zero cnt for the histogram) ----------------

__global__ void cvt16_kernel(const float* __restrict__ xin, _Float16* __restrict__ x16,
                             int total8, int* __restrict__ cnt, int N) {
    int i = blockIdx.x * blockDim.x + threadIdx.x;
    if (i < N) cnt[i] = 0;
    if (i >= total8) return;
    const float4* p = reinterpret_cast<const float4*>(xin + (size_t)i * 8);
    float4 a = p[0], b = p[1];
    h8 o;
    o[0] = (_Float16)a.x; o[1] = (_Float16)a.y; o[2] = (_Float16)a.z; o[3] = (_Float16)a.w;
    o[4] = (_Float16)b.x; o[5] = (_Float16)b.y; o[6] = (_Float16)b.z; o[7] = (_Float16)b.w;
    *reinterpret_cast<h8*>(x16 + (size_t)i * 8) = o;
}

// ---------------- CSR build: hist + scan + counting-sort partition ----------------

__global__ void hist_kernel(const int* __restrict__ dst, int E, int* __restrict__ cnt) {
    int e = blockIdx.x * blockDim.x + threadIdx.x;
    if (e < E) atomicAdd(&cnt[dst[e]], 1);
}

__global__ __launch_bounds__(256) void bsum_kernel(const int* __restrict__ cnt, int N,
                                                   int* __restrict__ bsum) {
    __shared__ int red[256];
    int t = threadIdx.x;
    int i = blockIdx.x * 256 + t;
    red[t] = (i < N) ? cnt[i] : 0;
    __syncthreads();
    for (int off = 128; off > 0; off >>= 1) {
        if (t < off) red[t] += red[t + off];
        __syncthreads();
    }
    if (t == 0) bsum[blockIdx.x] = red[0];
}

// Each block redundantly scans the (<=256) block sums, then scans its own 256
// counts; writes row_start (incl. row_start[N]=E), bucket cursors, zeroes pooled.
__global__ __launch_bounds__(256) void scan_apply_kernel(const int* __restrict__ cnt, int N,
                                                         const int* __restrict__ bsum, int nb,
                                                         int* __restrict__ row_start,
                                                         int* __restrict__ bcur,
                                                         unsigned int* __restrict__ pooled) {
    __shared__ int sb[256];
    __shared__ int s[256];
    int t = threadIdx.x;
    if (blockIdx.x == 0)
        for (int k = t; k < 64 * 128; k += 256) pooled[k] = 0u;
    sb[t] = (t < nb) ? bsum[t] : 0;
    int i = blockIdx.x * 256 + t;
    int v = (i < N) ? cnt[i] : 0;
    s[t] = v;
    __syncthreads();
    for (int off = 1; off < 256; off <<= 1) {
        int u0 = (t >= off) ? sb[t - off] : 0;
        int u1 = (t >= off) ? s[t - off] : 0;
        __syncthreads();
        sb[t] += u0;
        s[t] += u1;
        __syncthreads();
    }
    int base = (blockIdx.x == 0) ? 0 : sb[blockIdx.x - 1];
    int excl = base + s[t] - v;
    if (i < N) {
        row_start[i] = excl;
        if ((i & 63) == 0) bcur[i >> 6] = excl;   // bucket = 64 nodes
        if (i == N - 1) row_start[N] = excl + v;  // = E
    }
}

// Pass A (counting-sort style): LDS histogram per block, one global atomicAdd
// per non-empty bucket per block, then LDS-cursor ranked packed writes.
// EPB=2048 -> ~391 blocks: enough TLP to cover the sweep latency (R10: 8192
// gave only 98 blocks, 3.3% occupancy, 40 us).
#define EPB 2048

__global__ __launch_bounds__(256) void partA_kernel(const int* __restrict__ src,
                                                    const int* __restrict__ dst, int E,
                                                    int nbkt, int* __restrict__ bcur,
                                                    unsigned int* __restrict__ pk) {
    __shared__ int lh[1024];
    __shared__ int lbase[1024];
    int t = threadIdx.x;
    int e0 = blockIdx.x * EPB;
    int e1 = e0 + EPB; if (e1 > E) e1 = E;
    for (int b = t; b < nbkt; b += 256) lh[b] = 0;
    __syncthreads();
    for (int e = e0 + t; e < e1; e += 256)
        atomicAdd(&lh[dst[e] >> 6], 1);
    __syncthreads();
    for (int b = t; b < nbkt; b += 256) {
        int c = lh[b];
        lbase[b] = (c > 0) ? atomicAdd(&bcur[b], c) : 0;
        lh[b] = 0;
    }
    __syncthreads();
    for (int e = e0 + t; e < e1; e += 256) {
        int d = dst[e];
        int b = d >> 6;
        int r = atomicAdd(&lh[b], 1);
        pk[lbase[b] + r] = ((unsigned int)src[e] << 6) | (unsigned int)(d & 63);
    }
}

// Pass B: one block per bucket; LDS cursors rank edges within each node.
__global__ __launch_bounds__(256) void partB_kernel(const unsigned int* __restrict__ pk,
                                                    const int* __restrict__ row_start,
                                                    int N, int E, int* __restrict__ col) {
    __shared__ int lrs[64];
    __shared__ int lcur[64];
    int b = blockIdx.x;
    int base = b * 64;
    int t = threadIdx.x;
    if (t < 64) {
        int node = base + t;
        lrs[t] = (node < N) ? row_start[node] : E;
        lcur[t] = 0;
    }
    __syncthreads();
    int lo = row_start[base];
    int nxt = base + 64; if (nxt > N) nxt = N;
    int hi = row_start[nxt];
    for (int i = lo + t; i < hi; i += 256) {
        unsigned int w = pk[i];
        int dl = w & 63u;
        int s = (int)(w >> 6);
        int r = atomicAdd(&lcur[dl], 1);
        col[lrs[dl] + r] = s;
    }
}

// ---------------- max aggregation (fp16): 32 lanes/node, h4, 4-way unrolled ----------------
// Proven-best shape (R5/R8/R10): 2 nodes/wave, ~12 VGPR -> full occupancy, 25k
// waves; 4 independent accumulators break the col->gather->max latency chain.

__global__ __launch_bounds__(256) void agg_kernel(const _Float16* __restrict__ x16,
                                                  const int* __restrict__ row_start,
                                                  const int* __restrict__ col,
                                                  _Float16* __restrict__ agg16, int N) {
    int gid = blockIdx.x * blockDim.x + threadIdx.x;
    int node = gid >> 5;
    int lane = gid & 31;
    if (node >= N) return;
    int beg = row_start[node];
    int deg = row_start[node + 1] - beg;
    const _Float16 NEG = (_Float16)(-65504.0f);
    h4 a0, a1, a2, a3;
    a0[0] = NEG; a0[1] = NEG; a0[2] = NEG; a0[3] = NEG;
    a1 = a0; a2 = a0; a3 = a0;
    int j = 0;
    for (; j + 4 <= deg; j += 4) {
        int s0 = col[beg + j];
        int s1 = col[beg + j + 1];
        int s2 = col[beg + j + 2];
        int s3 = col[beg + j + 3];
        h4 v0 = *reinterpret_cast<const h4*>(&x16[(size_t)s0 * 128 + lane * 4]);
        h4 v1 = *reinterpret_cast<const h4*>(&x16[(size_t)s1 * 128 + lane * 4]);
        h4 v2 = *reinterpret_cast<const h4*>(&x16[(size_t)s2 * 128 + lane * 4]);
        h4 v3 = *reinterpret_cast<const h4*>(&x16[(size_t)s3 * 128 + lane * 4]);
        a0 = h4max(a0, v0);
        a1 = h4max(a1, v1);
        a2 = h4max(a2, v2);
        a3 = h4max(a3, v3);
    }
    for (; j < deg; ++j) {
        int s0 = col[beg + j];
        h4 v0 = *reinterpret_cast<const h4*>(&x16[(size_t)s0 * 128 + lane * 4]);
        a0 = h4max(a0, v0);
    }
    a0 = h4max(h4max(a0, a1), h4max(a2, a3));
    if (deg == 0) { a0[0] = (_Float16)0.f; a0[1] = (_Float16)0.f; a0[2] = (_Float16)0.f; a0[3] = (_Float16)0.f; }
    *reinterpret_cast<h4*>(&agg16[(size_t)node * 128 + lane * 4]) = a0;
}

// ---------------- W prep: split fp32 W into bf16 hi/lo, fragment-ordered ----------------
// dest layout per layer: [phase(2)][kgroup(16)][col(128)][j(8)].

__global__ void wprep_kernel(const float* __restrict__ Wn, const float* __restrict__ Wsf,
                             int total, unsigned short* __restrict__ Wfh,
                             unsigned short* __restrict__ Wfl) {
    int idx = blockIdx.x * blockDim.x + threadIdx.x;
    if (idx >= total) return;
    int c = idx & 127;
    int k = (idx >> 7) & 127;
    int p = (idx >> 14) & 1;
    int l = idx >> 15;
    const float* W = p ? Wsf : Wn;
    float v = W[(size_t)l * 16384 + k * 128 + c];
    unsigned short hi = f2bh(v);
    unsigned short lo = f2bh(v - bh2f(hi));
    size_t d = ((((size_t)l * 2 + p) * 16 + (k >> 3)) * 128 + c) * 8 + (k & 7);
    Wfh[d] = hi;
    Wfl[d] = lo;
}

// ---------------- layer GEMM via MFMA: relu([agg|x]@[Wn;Ws] + b) ----------------
// 16 rows x 64 cols per wave -> 6250 waves for latency hiding.
// 3-term split-bf16 (Ah@Wh + Al@Wh + Ah@Wl); fp16 A splits exactly into bf16 hi+lo.

__global__ __launch_bounds__(256) void layer_mfma(
    const _Float16* __restrict__ agg16, const _Float16* __restrict__ xin16,
    const unsigned short* __restrict__ Wfh, const unsigned short* __restrict__ Wfl,
    const float* __restrict__ bias, _Float16* __restrict__ xout16, int N)
{
    const int lane = threadIdx.x & 63;
    const int wid  = threadIdx.x >> 6;   // 0..3
    const int l15  = lane & 15;
    const int lg   = lane >> 4;          // 0..3
    const int ch   = wid & 1;            // col half
    const int rg   = wid >> 1;           // row group
    const int row0 = blockIdx.x * 32 + rg * 16;

    f32x4 acc[4];
    #pragma unroll
    for (int nt = 0; nt < 4; ++nt) { f32x4 z = {0.f, 0.f, 0.f, 0.f}; acc[nt] = z; }

    int rc = row0 + l15; if (rc > N - 1) rc = N - 1;

    #pragma unroll
    for (int p = 0; p < 2; ++p) {
        const _Float16* A = p ? xin16 : agg16;
        const _Float16* a = A + (size_t)rc * 128 + lg * 8;
        const unsigned short* wh0 = Wfh + p * 16384 + (size_t)(ch * 64 + l15) * 8 + lg * 1024;
        const unsigned short* wl0 = Wfl + p * 16384 + (size_t)(ch * 64 + l15) * 8 + lg * 1024;
        #pragma unroll
        for (int ks = 0; ks < 4; ++ks) {
            h8 av = *reinterpret_cast<const h8*>(a + ks * 32);
            ushort8 hh, ll;
            #pragma unroll
            for (int j = 0; j < 8; ++j) {
                float f = (float)av[j];
                unsigned short hi = f2bh(f);
                float r = f - bh2f(hi);          // exactly representable in bf16
                hh[j] = hi;
                ll[j] = (unsigned short)(__float_as_uint(r) >> 16);
            }
            bf16x8 ah = __builtin_bit_cast(bf16x8, hh);
            bf16x8 al = __builtin_bit_cast(bf16x8, ll);
            const unsigned short* whk = wh0 + ks * 4096;
            const unsigned short* wlk = wl0 + ks * 4096;
            #pragma unroll
            for (int nt = 0; nt < 4; ++nt) {
                bf16x8 bh = *reinterpret_cast<const bf16x8*>(whk + nt * 128);
                bf16x8 bl = *reinterpret_cast<const bf16x8*>(wlk + nt * 128);
                acc[nt] = __builtin_amdgcn_mfma_f32_16x16x32_bf16(ah, bh, acc[nt], 0, 0, 0);
                acc[nt] = __builtin_amdgcn_mfma_f32_16x16x32_bf16(al, bh, acc[nt], 0, 0, 0);
                acc[nt] = __builtin_amdgcn_mfma_f32_16x16x32_bf16(ah, bl, acc[nt], 0, 0, 0);
            }
        }
    }

    #pragma unroll
    for (int nt = 0; nt < 4; ++nt) {
        int colb = ch * 64 + nt * 16 + l15;
        float bv = bias[colb];
        #pragma unroll
        for (int rr = 0; rr < 4; ++rr) {
            int row = row0 + lg * 4 + rr;
            if (row < N) {
                float o = fmaxf(acc[nt][rr] + bv, 0.f);
                xout16[(size_t)row * 128 + colb] = (_Float16)o;
            }
        }
    }
}

// ---------------- global max pool per graph: chunked + atomicMax ----------------

#define POOL_CHUNK 128

__global__ __launch_bounds__(128) void pool_kernel(const _Float16* __restrict__ x16,
                                                   const int* __restrict__ batch,
                                                   int N,
                                                   unsigned int* __restrict__ pooled) {
    int f = threadIdx.x;
    int n0 = blockIdx.x * POOL_CHUNK;
    if (n0 >= N) return;
    int n1 = n0 + POOL_CHUNK; if (n1 > N) n1 = N;
    int g = batch[n0];
    float m = 0.f;
    for (int n = n0; n < n1; ++n) {
        int bg = batch[n];
        if (bg != g) {
            atomicMax(&pooled[g * 128 + f], __float_as_uint(m));
            m = 0.f; g = bg;
        }
        m = fmaxf(m, (float)x16[(size_t)n * 128 + f]);
    }
    atomicMax(&pooled[g * 128 + f], __float_as_uint(m));
}

// ---------------- head ----------------

__global__ __launch_bounds__(256) void head_kernel(
    const float* __restrict__ pooled,
    const float* __restrict__ linW, const float* __restrict__ linb,
    const float* __restrict__ outW, const float* __restrict__ outb,
    float* __restrict__ out)
{
    __shared__ float pl[128];
    __shared__ float hrow[256];
    int g = blockIdx.x, t = threadIdx.x;
    if (t < 128) pl[t] = pooled[g * 128 + t];
    __syncthreads();
    float acc = linb[t];
    for (int k = 0; k < 128; ++k) acc += pl[k] * linW[k * 256 + t];
    hrow[t] = acc;
    __syncthreads();
    if (t < 10) {
        float o = outb[t];
        for (int k = 0; k < 256; ++k) o += hrow[k] * outW[k * 10 + t];
        out[g * 10 + t] = o;
    }
}

// ---------------- launch ----------------

static inline size_t align_up(size_t v, size_t a) { return (v + a - 1) & ~(a - 1); }

extern "C" void kernel_launch(void* const* d_in, const int* in_sizes, int n_in,
                              void* d_out, int out_size, void* d_ws, size_t ws_size,
                              hipStream_t stream) {
    const float* x      = (const float*)d_in[0];
    const int*   ei     = (const int*)d_in[1];
    const int*   batch  = (const int*)d_in[2];
    const float* WsSelf = (const float*)d_in[3];
    const float* WsNei  = (const float*)d_in[4];
    const float* bsAll  = (const float*)d_in[5];
    const float* linW   = (const float*)d_in[6];
    const float* linb   = (const float*)d_in[7];
    const float* outW   = (const float*)d_in[8];
    const float* outb   = (const float*)d_in[9];

    const int N = in_sizes[0] / 128;
    const int E = in_sizes[1] / 2;
    const int L = in_sizes[3] / (128 * 128);
    const int* src = ei;
    const int* dst = ei + E;
    const int nb2 = (N + 63) / 64;     // 64-node buckets (<=1024 assumed)

    // workspace carve
    char* w = (char*)d_ws;
    int* cnt       = (int*)w;  w += align_up((size_t)N * 4, 256);
    int* row_start = (int*)w;  w += align_up((size_t)(N + 1) * 4, 256);
    int* bcur      = (int*)w;  w += align_up((size_t)nb2 * 4, 256);
    int* bsum      = (int*)w;  w += align_up(256 * 4, 256);
    unsigned int* pk = (unsigned int*)w; w += align_up((size_t)E * 4, 256);
    int* col       = (int*)w;  w += align_up((size_t)E * 4, 256);
    _Float16* agg16 = (_Float16*)w; w += align_up((size_t)N * 128 * 2, 256);
    _Float16* x16in = (_Float16*)w; w += align_up((size_t)N * 128 * 2, 256);
    _Float16* xa16  = (_Float16*)w; w += align_up((size_t)N * 128 * 2, 256);
    _Float16* xb16  = (_Float16*)w; w += align_up((size_t)N * 128 * 2, 256);
    float* pooled  = (float*)w; w += align_up((size_t)64 * 128 * 4, 256);
    unsigned short* Wfh = (unsigned short*)w; w += align_up((size_t)L * 2 * 16384 * 2, 256);
    unsigned short* Wfl = (unsigned short*)w; w += align_up((size_t)L * 2 * 16384 * 2, 256);
    (void)ws_size;

    cvt16_kernel<<<(N * 16 + 255) / 256, 256, 0, stream>>>(x, x16in, N * 16, cnt, N);

    const int wtotal = L * 2 * 128 * 128;
    wprep_kernel<<<(wtotal + 255) / 256, 256, 0, stream>>>(WsNei, WsSelf, wtotal, Wfh, Wfl);

    const int nb = (N + 255) / 256;
    hist_kernel<<<(E + 255) / 256, 256, 0, stream>>>(dst, E, cnt);
    bsum_kernel<<<nb, 256, 0, stream>>>(cnt, N, bsum);
    scan_apply_kernel<<<nb, 256, 0, stream>>>(cnt, N, bsum, nb, row_start, bcur,
                                              (unsigned int*)pooled);
    partA_kernel<<<(E + EPB - 1) / EPB, 256, 0, stream>>>(src, dst, E, nb2, bcur, pk);
    partB_kernel<<<nb2, 256, 0, stream>>>(pk, row_start, N, E, col);

    const _Float16* xin16 = x16in;
    _Float16* bufs[2] = { xa16, xb16 };
    for (int l = 0; l < L; ++l) {
        agg_kernel<<<(N * 32 + 255) / 256, 256, 0, stream>>>(xin16, row_start, col, agg16, N);
        layer_mfma<<<(N + 31) / 32, 256, 0, stream>>>(
            agg16, xin16,
            Wfh + (size_t)l * 2 * 16384, Wfl + (size_t)l * 2 * 16384,
            bsAll + (size_t)l * 128, bufs[l & 1], N);
        xin16 = bufs[l & 1];
    }

    pool_kernel<<<(N + POOL_CHUNK - 1) / POOL_CHUNK, 128, 0, stream>>>(
        xin16, batch, N, (unsigned int*)pooled);
    head_kernel<<<64, 256, 0, stream>>>(pooled, linW, linb, outW, outb, (float*)d_out);
}

// Round 13
// 288.937 us; speedup vs baseline: 1.1261x; 1.0258x over previous
//
#include <hip/hip_runtime.h>
#include <float.h>

typedef __bf16 bf16x8 __attribute__((ext_vector_type(8)));
typedef float f32x4 __attribute__((ext_vector_type(4)));
typedef unsigned short ushort8 __attribute__((ext_vector_type(8)));
typedef _Float16 h8 __attribute__((ext_vector_type(8)));
typedef _Float16 h4 __attribute__((ext_vector_type(4)));

__device__ inline unsigned short f2bh(float f) {
    unsigned int u = __float_as_uint(f);
    return (unsigned short)((u + 0x7FFFu + ((u >> 16) & 1u)) >> 16);
}
__device__ inline float bh2f(unsigned short h) {
    return __uint_as_float((unsigned int)h << 16);
}
__device__ inline h4 h4max(h4 a, h4 b) {
    h4 r;
    r[0] = a[0] > b[0] ? a[0] : b[0];
    r[1] = a[1] > b[1] ? a[1] : b[1];
    r[2] = a[2] > b[2] ? a[2] : b[2];
    r[3] = a[3] > b[3] ? a[3] : b[3];
    return r;
}

// ---------------- fp32 -> fp16 convert (+ zero cnt for the histogram) ----------------

__global__ void cvt16_kernel(const float* __restrict__ xin, _Float16* __restrict__ x16,
                             int total8, int* __restrict__ cnt, int N) {
    int i = blockIdx.x * blockDim.x + threadIdx.x;
    if (i < N) cnt[i] = 0;
    if (i >= total8) return;
    const float4* p = reinterpret_cast<const float4*>(xin + (size_t)i * 8);
    float4 a = p[0], b = p[1];
    h8 o;
    o[0] = (_Float16)a.x; o[1] = (_Float16)a.y; o[2] = (_Float16)a.z; o[3] = (_Float16)a.w;
    o[4] = (_Float16)b.x; o[5] = (_Float16)b.y; o[6] = (_Float16)b.z; o[7] = (_Float16)b.w;
    *reinterpret_cast<h8*>(x16 + (size_t)i * 8) = o;
}

// ---------------- CSR build: hist + scan + counting-sort partition ----------------

__global__ void hist_kernel(const int* __restrict__ dst, int E, int* __restrict__ cnt) {
    int e = blockIdx.x * blockDim.x + threadIdx.x;
    if (e < E) atomicAdd(&cnt[dst[e]], 1);
}

__global__ __launch_bounds__(256) void bsum_kernel(const int* __restrict__ cnt, int N,
                                                   int* __restrict__ bsum) {
    __shared__ int red[256];
    int t = threadIdx.x;
    int i = blockIdx.x * 256 + t;
    red[t] = (i < N) ? cnt[i] : 0;
    __syncthreads();
    for (int off = 128; off > 0; off >>= 1) {
        if (t < off) red[t] += red[t + off];
        __syncthreads();
    }
    if (t == 0) bsum[blockIdx.x] = red[0];
}

// Each block redundantly scans the (<=256) block sums, then scans its own 256
// counts; writes row_start (incl. row_start[N]=E), bucket cursors, zeroes pooled.
__global__ __launch_bounds__(256) void scan_apply_kernel(const int* __restrict__ cnt, int N,
                                                         const int* __restrict__ bsum, int nb,
                                                         int* __restrict__ row_start,
                                                         int* __restrict__ bcur,
                                                         unsigned int* __restrict__ pooled) {
    __shared__ int sb[256];
    __shared__ int s[256];
    int t = threadIdx.x;
    if (blockIdx.x == 0)
        for (int k = t; k < 64 * 128; k += 256) pooled[k] = 0u;
    sb[t] = (t < nb) ? bsum[t] : 0;
    int i = blockIdx.x * 256 + t;
    int v = (i < N) ? cnt[i] : 0;
    s[t] = v;
    __syncthreads();
    for (int off = 1; off < 256; off <<= 1) {
        int u0 = (t >= off) ? sb[t - off] : 0;
        int u1 = (t >= off) ? s[t - off] : 0;
        __syncthreads();
        sb[t] += u0;
        s[t] += u1;
        __syncthreads();
    }
    int base = (blockIdx.x == 0) ? 0 : sb[blockIdx.x - 1];
    int excl = base + s[t] - v;
    if (i < N) {
        row_start[i] = excl;
        if ((i & 63) == 0) bcur[i >> 6] = excl;   // bucket = 64 nodes
        if (i == N - 1) row_start[N] = excl + v;  // = E
    }
}

// Pass A (counting-sort style): LDS histogram per block, one global atomicAdd
// per non-empty bucket per block, then LDS-cursor ranked packed writes.
#define EPB 2048

__global__ __launch_bounds__(256) void partA_kernel(const int* __restrict__ src,
                                                    const int* __restrict__ dst, int E,
                                                    int nbkt, int* __restrict__ bcur,
                                                    unsigned int* __restrict__ pk) {
    __shared__ int lh[1024];
    __shared__ int lbase[1024];
    int t = threadIdx.x;
    int e0 = blockIdx.x * EPB;
    int e1 = e0 + EPB; if (e1 > E) e1 = E;
    for (int b = t; b < nbkt; b += 256) lh[b] = 0;
    __syncthreads();
    for (int e = e0 + t; e < e1; e += 256)
        atomicAdd(&lh[dst[e] >> 6], 1);
    __syncthreads();
    for (int b = t; b < nbkt; b += 256) {
        int c = lh[b];
        lbase[b] = (c > 0) ? atomicAdd(&bcur[b], c) : 0;
        lh[b] = 0;
    }
    __syncthreads();
    for (int e = e0 + t; e < e1; e += 256) {
        int d = dst[e];
        int b = d >> 6;
        int r = atomicAdd(&lh[b], 1);
        pk[lbase[b] + r] = ((unsigned int)src[e] << 6) | (unsigned int)(d & 63);
    }
}

// Pass B: one block per bucket; LDS cursors rank edges within each node.
__global__ __launch_bounds__(256) void partB_kernel(const unsigned int* __restrict__ pk,
                                                    const int* __restrict__ row_start,
                                                    int N, int E, int* __restrict__ col) {
    __shared__ int lrs[64];
    __shared__ int lcur[64];
    int b = blockIdx.x;
    int base = b * 64;
    int t = threadIdx.x;
    if (t < 64) {
        int node = base + t;
        lrs[t] = (node < N) ? row_start[node] : E;
        lcur[t] = 0;
    }
    __syncthreads();
    int lo = row_start[base];
    int nxt = base + 64; if (nxt > N) nxt = N;
    int hi = row_start[nxt];
    for (int i = lo + t; i < hi; i += 256) {
        unsigned int w = pk[i];
        int dl = w & 63u;
        int s = (int)(w >> 6);
        int r = atomicAdd(&lcur[dl], 1);
        col[lrs[dl] + r] = s;
    }
}

// ---------------- max aggregation (fp16): 32 lanes/node, h4, 8-way unrolled ----------------
// 32-lane shape proven best (R10). 8 independent accumulators -> 16 gathers in
// flight per wave. Clamped-index padding (repeat last edge) removes the serial
// dependent remainder loop entirely; repeats are harmless under max.

__global__ __launch_bounds__(256) void agg_kernel(const _Float16* __restrict__ x16,
                                                  const int* __restrict__ row_start,
                                                  const int* __restrict__ col,
                                                  _Float16* __restrict__ agg16, int N) {
    int gid = blockIdx.x * blockDim.x + threadIdx.x;
    int node = gid >> 5;
    int lane = gid & 31;
    if (node >= N) return;
    int beg = row_start[node];
    int deg = row_start[node + 1] - beg;
    if (deg == 0) {
        h4 z; z[0] = (_Float16)0.f; z[1] = (_Float16)0.f; z[2] = (_Float16)0.f; z[3] = (_Float16)0.f;
        *reinterpret_cast<h4*>(&agg16[(size_t)node * 128 + lane * 4]) = z;
        return;
    }
    const _Float16 NEG = (_Float16)(-65504.0f);
    h4 a0, a1, a2, a3, a4, a5, a6, a7;
    a0[0] = NEG; a0[1] = NEG; a0[2] = NEG; a0[3] = NEG;
    a1 = a0; a2 = a0; a3 = a0; a4 = a0; a5 = a0; a6 = a0; a7 = a0;
    int dm1 = deg - 1;
    for (int j = 0; j < deg; j += 8) {
        int j1 = j + 1 > dm1 ? dm1 : j + 1;
        int j2 = j + 2 > dm1 ? dm1 : j + 2;
        int j3 = j + 3 > dm1 ? dm1 : j + 3;
        int j4 = j + 4 > dm1 ? dm1 : j + 4;
        int j5 = j + 5 > dm1 ? dm1 : j + 5;
        int j6 = j + 6 > dm1 ? dm1 : j + 6;
        int j7 = j + 7 > dm1 ? dm1 : j + 7;
        int s0 = col[beg + j];
        int s1 = col[beg + j1];
        int s2 = col[beg + j2];
        int s3 = col[beg + j3];
        int s4 = col[beg + j4];
        int s5 = col[beg + j5];
        int s6 = col[beg + j6];
        int s7 = col[beg + j7];
        a0 = h4max(a0, *reinterpret_cast<const h4*>(&x16[(size_t)s0 * 128 + lane * 4]));
        a1 = h4max(a1, *reinterpret_cast<const h4*>(&x16[(size_t)s1 * 128 + lane * 4]));
        a2 = h4max(a2, *reinterpret_cast<const h4*>(&x16[(size_t)s2 * 128 + lane * 4]));
        a3 = h4max(a3, *reinterpret_cast<const h4*>(&x16[(size_t)s3 * 128 + lane * 4]));
        a4 = h4max(a4, *reinterpret_cast<const h4*>(&x16[(size_t)s4 * 128 + lane * 4]));
        a5 = h4max(a5, *reinterpret_cast<const h4*>(&x16[(size_t)s5 * 128 + lane * 4]));
        a6 = h4max(a6, *reinterpret_cast<const h4*>(&x16[(size_t)s6 * 128 + lane * 4]));
        a7 = h4max(a7, *reinterpret_cast<const h4*>(&x16[(size_t)s7 * 128 + lane * 4]));
    }
    a0 = h4max(h4max(h4max(a0, a1), h4max(a2, a3)),
               h4max(h4max(a4, a5), h4max(a6, a7)));
    *reinterpret_cast<h4*>(&agg16[(size_t)node * 128 + lane * 4]) = a0;
}

// ---------------- W prep: split fp32 W into bf16 hi/lo, fragment-ordered ----------------
// dest layout per layer: [phase(2)][kgroup(16)][col(128)][j(8)].

__global__ void wprep_kernel(const float* __restrict__ Wn, const float* __restrict__ Wsf,
                             int total, unsigned short* __restrict__ Wfh,
                             unsigned short* __restrict__ Wfl) {
    int idx = blockIdx.x * blockDim.x + threadIdx.x;
    if (idx >= total) return;
    int c = idx & 127;
    int k = (idx >> 7) & 127;
    int p = (idx >> 14) & 1;
    int l = idx >> 15;
    const float* W = p ? Wsf : Wn;
    float v = W[(size_t)l * 16384 + k * 128 + c];
    unsigned short hi = f2bh(v);
    unsigned short lo = f2bh(v - bh2f(hi));
    size_t d = ((((size_t)l * 2 + p) * 16 + (k >> 3)) * 128 + c) * 8 + (k & 7);
    Wfh[d] = hi;
    Wfl[d] = lo;
}

// ---------------- layer GEMM via MFMA: relu([agg|x]@[Wn;Ws] + b) ----------------
// 16 rows x 64 cols per wave -> 6250 waves for latency hiding.
// 3-term split-bf16 (Ah@Wh + Al@Wh + Ah@Wl); fp16 A splits exactly into bf16 hi+lo.

__global__ __launch_bounds__(256) void layer_mfma(
    const _Float16* __restrict__ agg16, const _Float16* __restrict__ xin16,
    const unsigned short* __restrict__ Wfh, const unsigned short* __restrict__ Wfl,
    const float* __restrict__ bias, _Float16* __restrict__ xout16, int N)
{
    const int lane = threadIdx.x & 63;
    const int wid  = threadIdx.x >> 6;   // 0..3
    const int l15  = lane & 15;
    const int lg   = lane >> 4;          // 0..3
    const int ch   = wid & 1;            // col half
    const int rg   = wid >> 1;           // row group
    const int row0 = blockIdx.x * 32 + rg * 16;

    f32x4 acc[4];
    #pragma unroll
    for (int nt = 0; nt < 4; ++nt) { f32x4 z = {0.f, 0.f, 0.f, 0.f}; acc[nt] = z; }

    int rc = row0 + l15; if (rc > N - 1) rc = N - 1;

    #pragma unroll
    for (int p = 0; p < 2; ++p) {
        const _Float16* A = p ? xin16 : agg16;
        const _Float16* a = A + (size_t)rc * 128 + lg * 8;
        const unsigned short* wh0 = Wfh + p * 16384 + (size_t)(ch * 64 + l15) * 8 + lg * 1024;
        const unsigned short* wl0 = Wfl + p * 16384 + (size_t)(ch * 64 + l15) * 8 + lg * 1024;
        #pragma unroll
        for (int ks = 0; ks < 4; ++ks) {
            h8 av = *reinterpret_cast<const h8*>(a + ks * 32);
            ushort8 hh, ll;
            #pragma unroll
            for (int j = 0; j < 8; ++j) {
                float f = (float)av[j];
                unsigned short hi = f2bh(f);
                float r = f - bh2f(hi);          // exactly representable in bf16
                hh[j] = hi;
                ll[j] = (unsigned short)(__float_as_uint(r) >> 16);
            }
            bf16x8 ah = __builtin_bit_cast(bf16x8, hh);
            bf16x8 al = __builtin_bit_cast(bf16x8, ll);
            const unsigned short* whk = wh0 + ks * 4096;
            const unsigned short* wlk = wl0 + ks * 4096;
            #pragma unroll
            for (int nt = 0; nt < 4; ++nt) {
                bf16x8 bh = *reinterpret_cast<const bf16x8*>(whk + nt * 128);
                bf16x8 bl = *reinterpret_cast<const bf16x8*>(wlk + nt * 128);
                acc[nt] = __builtin_amdgcn_mfma_f32_16x16x32_bf16(ah, bh, acc[nt], 0, 0, 0);
                acc[nt] = __builtin_amdgcn_mfma_f32_16x16x32_bf16(al, bh, acc[nt], 0, 0, 0);
                acc[nt] = __builtin_amdgcn_mfma_f32_16x16x32_bf16(ah, bl, acc[nt], 0, 0, 0);
            }
        }
    }

    #pragma unroll
    for (int nt = 0; nt < 4; ++nt) {
        int colb = ch * 64 + nt * 16 + l15;
        float bv = bias[colb];
        #pragma unroll
        for (int rr = 0; rr < 4; ++rr) {
            int row = row0 + lg * 4 + rr;
            if (row < N) {
                float o = fmaxf(acc[nt][rr] + bv, 0.f);
                xout16[(size_t)row * 128 + colb] = (_Float16)o;
            }
        }
    }
}

// ---------------- global max pool per graph: chunked + atomicMax ----------------

#define POOL_CHUNK 128

__global__ __launch_bounds__(128) void pool_kernel(const _Float16* __restrict__ x16,
                                                   const int* __restrict__ batch,
                                                   int N,
                                                   unsigned int* __restrict__ pooled) {
    int f = threadIdx.x;
    int n0 = blockIdx.x * POOL_CHUNK;
    if (n0 >= N) return;
    int n1 = n0 + POOL_CHUNK; if (n1 > N) n1 = N;
    int g = batch[n0];
    float m = 0.f;
    for (int n = n0; n < n1; ++n) {
        int bg = batch[n];
        if (bg != g) {
            atomicMax(&pooled[g * 128 + f], __float_as_uint(m));
            m = 0.f; g = bg;
        }
        m = fmaxf(m, (float)x16[(size_t)n * 128 + f]);
    }
    atomicMax(&pooled[g * 128 + f], __float_as_uint(m));
}

// ---------------- head ----------------

__global__ __launch_bounds__(256) void head_kernel(
    const float* __restrict__ pooled,
    const float* __restrict__ linW, const float* __restrict__ linb,
    const float* __restrict__ outW, const float* __restrict__ outb,
    float* __restrict__ out)
{
    __shared__ float pl[128];
    __shared__ float hrow[256];
    int g = blockIdx.x, t = threadIdx.x;
    if (t < 128) pl[t] = pooled[g * 128 + t];
    __syncthreads();
    float acc = linb[t];
    for (int k = 0; k < 128; ++k) acc += pl[k] * linW[k * 256 + t];
    hrow[t] = acc;
    __syncthreads();
    if (t < 10) {
        float o = outb[t];
        for (int k = 0; k < 256; ++k) o += hrow[k] * outW[k * 10 + t];
        out[g * 10 + t] = o;
    }
}

// ---------------- launch ----------------

static inline size_t align_up(size_t v, size_t a) { return (v + a - 1) & ~(a - 1); }

extern "C" void kernel_launch(void* const* d_in, const int* in_sizes, int n_in,
                              void* d_out, int out_size, void* d_ws, size_t ws_size,
                              hipStream_t stream) {
    const float* x      = (const float*)d_in[0];
    const int*   ei     = (const int*)d_in[1];
    const int*   batch  = (const int*)d_in[2];
    const float* WsSelf = (const float*)d_in[3];
    const float* WsNei  = (const float*)d_in[4];
    const float* bsAll  = (const float*)d_in[5];
    const float* linW   = (const float*)d_in[6];
    const float* linb   = (const float*)d_in[7];
    const float* outW   = (const float*)d_in[8];
    const float* outb   = (const float*)d_in[9];

    const int N = in_sizes[0] / 128;
    const int E = in_sizes[1] / 2;
    const int L = in_sizes[3] / (128 * 128);
    const int* src = ei;
    const int* dst = ei + E;
    const int nb2 = (N + 63) / 64;     // 64-node buckets (<=1024 assumed)

    // workspace carve
    char* w = (char*)d_ws;
    int* cnt       = (int*)w;  w += align_up((size_t)N * 4, 256);
    int* row_start = (int*)w;  w += align_up((size_t)(N + 1) * 4, 256);
    int* bcur      = (int*)w;  w += align_up((size_t)nb2 * 4, 256);
    int* bsum      = (int*)w;  w += align_up(256 * 4, 256);
    unsigned int* pk = (unsigned int*)w; w += align_up((size_t)E * 4, 256);
    int* col       = (int*)w;  w += align_up((size_t)E * 4, 256);
    _Float16* agg16 = (_Float16*)w; w += align_up((size_t)N * 128 * 2, 256);
    _Float16* x16in = (_Float16*)w; w += align_up((size_t)N * 128 * 2, 256);
    _Float16* xa16  = (_Float16*)w; w += align_up((size_t)N * 128 * 2, 256);
    _Float16* xb16  = (_Float16*)w; w += align_up((size_t)N * 128 * 2, 256);
    float* pooled  = (float*)w; w += align_up((size_t)64 * 128 * 4, 256);
    unsigned short* Wfh = (unsigned short*)w; w += align_up((size_t)L * 2 * 16384 * 2, 256);
    unsigned short* Wfl = (unsigned short*)w; w += align_up((size_t)L * 2 * 16384 * 2, 256);
    (void)ws_size;

    cvt16_kernel<<<(N * 16 + 255) / 256, 256, 0, stream>>>(x, x16in, N * 16, cnt, N);

    const int wtotal = L * 2 * 128 * 128;
    wprep_kernel<<<(wtotal + 255) / 256, 256, 0, stream>>>(WsNei, WsSelf, wtotal, Wfh, Wfl);

    const int nb = (N + 255) / 256;
    hist_kernel<<<(E + 255) / 256, 256, 0, stream>>>(dst, E, cnt);
    bsum_kernel<<<nb, 256, 0, stream>>>(cnt, N, bsum);
    scan_apply_kernel<<<nb, 256, 0, stream>>>(cnt, N, bsum, nb, row_start, bcur,
                                              (unsigned int*)pooled);
    partA_kernel<<<(E + EPB - 1) / EPB, 256, 0, stream>>>(src, dst, E, nb2, bcur, pk);
    partB_kernel<<<nb2, 256, 0, stream>>>(pk, row_start, N, E, col);

    const _Float16* xin16 = x16in;
    _Float16* bufs[2] = { xa16, xb16 };
    for (int l = 0; l < L; ++l) {
        agg_kernel<<<(N * 32 + 255) / 256, 256, 0, stream>>>(xin16, row_start, col, agg16, N);
        layer_mfma<<<(N + 31) / 32, 256, 0, stream>>>(
            agg16, xin16,
            Wfh + (size_t)l * 2 * 16384, Wfl + (size_t)l * 2 * 16384,
            bsAll + (size_t)l * 128, bufs[l & 1], N);
        xin16 = bufs[l & 1];
    }

    pool_kernel<<<(N + POOL_CHUNK - 1) / POOL_CHUNK, 128, 0, stream>>>(
        xin16, batch, N, (unsigned int*)pooled);
    head_kernel<<<64, 256, 0, stream>>>(pooled, linW, linb, outW, outb, (float*)d_out);
}

// Round 14
// 263.525 us; speedup vs baseline: 1.2347x; 1.0964x over previous
//
#include <hip/hip_runtime.h>
#include <float.h>

typedef __bf16 bf16x8 __attribute__((ext_vector_type(8)));
typedef float f32x4 __attribute__((ext_vector_type(4)));
typedef unsigned short ushort8 __attribute__((ext_vector_type(8)));
typedef _Float16 h8 __attribute__((ext_vector_type(8)));
typedef _Float16 h4 __attribute__((ext_vector_type(4)));

__device__ inline unsigned short f2bh(float f) {
    unsigned int u = __float_as_uint(f);
    return (unsigned short)((u + 0x7FFFu + ((u >> 16) & 1u)) >> 16);
}
__device__ inline float bh2f(unsigned short h) {
    return __uint_as_float((unsigned int)h << 16);
}
__device__ inline h4 h4max(h4 a, h4 b) {
    h4 r;
    r[0] = a[0] > b[0] ? a[0] : b[0];
    r[1] = a[1] > b[1] ? a[1] : b[1];
    r[2] = a[2] > b[2] ? a[2] : b[2];
    r[3] = a[3] > b[3] ? a[3] : b[3];
    return r;
}

// ---------------- fp32 -> fp16 convert (+ zero cnt for the histogram) ----------------

__global__ void cvt16_kernel(const float* __restrict__ xin, _Float16* __restrict__ x16,
                             int total8, int* __restrict__ cnt, int N) {
    int i = blockIdx.x * blockDim.x + threadIdx.x;
    if (i < N) cnt[i] = 0;
    if (i >= total8) return;
    const float4* p = reinterpret_cast<const float4*>(xin + (size_t)i * 8);
    float4 a = p[0], b = p[1];
    h8 o;
    o[0] = (_Float16)a.x; o[1] = (_Float16)a.y; o[2] = (_Float16)a.z; o[3] = (_Float16)a.w;
    o[4] = (_Float16)b.x; o[5] = (_Float16)b.y; o[6] = (_Float16)b.z; o[7] = (_Float16)b.w;
    *reinterpret_cast<h8*>(x16 + (size_t)i * 8) = o;
}

// ---------------- CSR build: hist + scan + counting-sort partition ----------------

__global__ void hist_kernel(const int* __restrict__ dst, int E, int* __restrict__ cnt) {
    int e = blockIdx.x * blockDim.x + threadIdx.x;
    if (e < E) atomicAdd(&cnt[dst[e]], 1);
}

__global__ __launch_bounds__(256) void bsum_kernel(const int* __restrict__ cnt, int N,
                                                   int* __restrict__ bsum) {
    __shared__ int red[256];
    int t = threadIdx.x;
    int i = blockIdx.x * 256 + t;
    red[t] = (i < N) ? cnt[i] : 0;
    __syncthreads();
    for (int off = 128; off > 0; off >>= 1) {
        if (t < off) red[t] += red[t + off];
        __syncthreads();
    }
    if (t == 0) bsum[blockIdx.x] = red[0];
}

// Each block redundantly scans the (<=256) block sums, then scans its own 256
// counts; writes row_start (incl. row_start[N]=E), bucket cursors, zeroes pooled.
__global__ __launch_bounds__(256) void scan_apply_kernel(const int* __restrict__ cnt, int N,
                                                         const int* __restrict__ bsum, int nb,
                                                         int* __restrict__ row_start,
                                                         int* __restrict__ bcur,
                                                         unsigned int* __restrict__ pooled) {
    __shared__ int sb[256];
    __shared__ int s[256];
    int t = threadIdx.x;
    if (blockIdx.x == 0)
        for (int k = t; k < 64 * 128; k += 256) pooled[k] = 0u;
    sb[t] = (t < nb) ? bsum[t] : 0;
    int i = blockIdx.x * 256 + t;
    int v = (i < N) ? cnt[i] : 0;
    s[t] = v;
    __syncthreads();
    for (int off = 1; off < 256; off <<= 1) {
        int u0 = (t >= off) ? sb[t - off] : 0;
        int u1 = (t >= off) ? s[t - off] : 0;
        __syncthreads();
        sb[t] += u0;
        s[t] += u1;
        __syncthreads();
    }
    int base = (blockIdx.x == 0) ? 0 : sb[blockIdx.x - 1];
    int excl = base + s[t] - v;
    if (i < N) {
        row_start[i] = excl;
        if ((i & 63) == 0) bcur[i >> 6] = excl;   // bucket = 64 nodes
        if (i == N - 1) row_start[N] = excl + v;  // = E
    }
}

// Pass A (counting-sort style): LDS histogram per block, one global atomicAdd
// per non-empty bucket per block, then LDS-cursor ranked packed writes.
// EPB=1024 -> ~782 blocks (~3 waves/SIMD): R11 showed latency scales ~linearly
// with TLP here; per-bucket global atomics stay ~2000x below R6's contention.
#define EPB 1024

__global__ __launch_bounds__(256) void partA_kernel(const int* __restrict__ src,
                                                    const int* __restrict__ dst, int E,
                                                    int nbkt, int* __restrict__ bcur,
                                                    unsigned int* __restrict__ pk) {
    __shared__ int lh[1024];
    __shared__ int lbase[1024];
    int t = threadIdx.x;
    int e0 = blockIdx.x * EPB;
    int e1 = e0 + EPB; if (e1 > E) e1 = E;
    for (int b = t; b < nbkt; b += 256) lh[b] = 0;
    __syncthreads();
    for (int e = e0 + t; e < e1; e += 256)
        atomicAdd(&lh[dst[e] >> 6], 1);
    __syncthreads();
    for (int b = t; b < nbkt; b += 256) {
        int c = lh[b];
        lbase[b] = (c > 0) ? atomicAdd(&bcur[b], c) : 0;
        lh[b] = 0;
    }
    __syncthreads();
    for (int e = e0 + t; e < e1; e += 256) {
        int d = dst[e];
        int b = d >> 6;
        int r = atomicAdd(&lh[b], 1);
        pk[lbase[b] + r] = ((unsigned int)src[e] << 6) | (unsigned int)(d & 63);
    }
}

// Pass B: one block per bucket; LDS cursors rank edges within each node.
__global__ __launch_bounds__(256) void partB_kernel(const unsigned int* __restrict__ pk,
                                                    const int* __restrict__ row_start,
                                                    int N, int E, int* __restrict__ col) {
    __shared__ int lrs[64];
    __shared__ int lcur[64];
    int b = blockIdx.x;
    int base = b * 64;
    int t = threadIdx.x;
    if (t < 64) {
        int node = base + t;
        lrs[t] = (node < N) ? row_start[node] : E;
        lcur[t] = 0;
    }
    __syncthreads();
    int lo = row_start[base];
    int nxt = base + 64; if (nxt > N) nxt = N;
    int hi = row_start[nxt];
    for (int i = lo + t; i < hi; i += 256) {
        unsigned int w = pk[i];
        int dl = w & 63u;
        int s = (int)(w >> 6);
        int r = atomicAdd(&lcur[dl], 1);
        col[lrs[dl] + r] = s;
    }
}

// ---------------- max aggregation (fp16): 32 lanes/node, h4, 8-way unrolled ----------------
// 32-lane shape proven best (R10); 8 independent accumulators + clamped-index
// padding (repeat last edge; harmless under max) -> no serial remainder loop.

__global__ __launch_bounds__(256) void agg_kernel(const _Float16* __restrict__ x16,
                                                  const int* __restrict__ row_start,
                                                  const int* __restrict__ col,
                                                  _Float16* __restrict__ agg16, int N) {
    int gid = blockIdx.x * blockDim.x + threadIdx.x;
    int node = gid >> 5;
    int lane = gid & 31;
    if (node >= N) return;
    int beg = row_start[node];
    int deg = row_start[node + 1] - beg;
    if (deg == 0) {
        h4 z; z[0] = (_Float16)0.f; z[1] = (_Float16)0.f; z[2] = (_Float16)0.f; z[3] = (_Float16)0.f;
        *reinterpret_cast<h4*>(&agg16[(size_t)node * 128 + lane * 4]) = z;
        return;
    }
    const _Float16 NEG = (_Float16)(-65504.0f);
    h4 a0, a1, a2, a3, a4, a5, a6, a7;
    a0[0] = NEG; a0[1] = NEG; a0[2] = NEG; a0[3] = NEG;
    a1 = a0; a2 = a0; a3 = a0; a4 = a0; a5 = a0; a6 = a0; a7 = a0;
    int dm1 = deg - 1;
    for (int j = 0; j < deg; j += 8) {
        int j1 = j + 1 > dm1 ? dm1 : j + 1;
        int j2 = j + 2 > dm1 ? dm1 : j + 2;
        int j3 = j + 3 > dm1 ? dm1 : j + 3;
        int j4 = j + 4 > dm1 ? dm1 : j + 4;
        int j5 = j + 5 > dm1 ? dm1 : j + 5;
        int j6 = j + 6 > dm1 ? dm1 : j + 6;
        int j7 = j + 7 > dm1 ? dm1 : j + 7;
        int s0 = col[beg + j];
        int s1 = col[beg + j1];
        int s2 = col[beg + j2];
        int s3 = col[beg + j3];
        int s4 = col[beg + j4];
        int s5 = col[beg + j5];
        int s6 = col[beg + j6];
        int s7 = col[beg + j7];
        a0 = h4max(a0, *reinterpret_cast<const h4*>(&x16[(size_t)s0 * 128 + lane * 4]));
        a1 = h4max(a1, *reinterpret_cast<const h4*>(&x16[(size_t)s1 * 128 + lane * 4]));
        a2 = h4max(a2, *reinterpret_cast<const h4*>(&x16[(size_t)s2 * 128 + lane * 4]));
        a3 = h4max(a3, *reinterpret_cast<const h4*>(&x16[(size_t)s3 * 128 + lane * 4]));
        a4 = h4max(a4, *reinterpret_cast<const h4*>(&x16[(size_t)s4 * 128 + lane * 4]));
        a5 = h4max(a5, *reinterpret_cast<const h4*>(&x16[(size_t)s5 * 128 + lane * 4]));
        a6 = h4max(a6, *reinterpret_cast<const h4*>(&x16[(size_t)s6 * 128 + lane * 4]));
        a7 = h4max(a7, *reinterpret_cast<const h4*>(&x16[(size_t)s7 * 128 + lane * 4]));
    }
    a0 = h4max(h4max(h4max(a0, a1), h4max(a2, a3)),
               h4max(h4max(a4, a5), h4max(a6, a7)));
    *reinterpret_cast<h4*>(&agg16[(size_t)node * 128 + lane * 4]) = a0;
}

// ---------------- W prep: split fp32 W into bf16 hi/lo, fragment-ordered ----------------
// dest layout per layer: [phase(2)][kgroup(16)][col(128)][j(8)].

__global__ void wprep_kernel(const float* __restrict__ Wn, const float* __restrict__ Wsf,
                             int total, unsigned short* __restrict__ Wfh,
                             unsigned short* __restrict__ Wfl) {
    int idx = blockIdx.x * blockDim.x + threadIdx.x;
    if (idx >= total) return;
    int c = idx & 127;
    int k = (idx >> 7) & 127;
    int p = (idx >> 14) & 1;
    int l = idx >> 15;
    const float* W = p ? Wsf : Wn;
    float v = W[(size_t)l * 16384 + k * 128 + c];
    unsigned short hi = f2bh(v);
    unsigned short lo = f2bh(v - bh2f(hi));
    size_t d = ((((size_t)l * 2 + p) * 16 + (k >> 3)) * 128 + c) * 8 + (k & 7);
    Wfh[d] = hi;
    Wfl[d] = lo;
}

// ---------------- layer GEMM via MFMA: relu([agg|x]@[Wn;Ws] + b) ----------------
// 16 rows x 64 cols per wave -> 6250 waves for latency hiding.
// 3-term split-bf16 (Ah@Wh + Al@Wh + Ah@Wl); fp16 A splits exactly into bf16 hi+lo.
// LAST=true: stage output tile in LDS, fused per-graph max-pool via atomicMax,
// skip the global xout write (pool was its only consumer).

template <bool LAST>
__global__ __launch_bounds__(256) void layer_mfma(
    const _Float16* __restrict__ agg16, const _Float16* __restrict__ xin16,
    const unsigned short* __restrict__ Wfh, const unsigned short* __restrict__ Wfl,
    const float* __restrict__ bias, _Float16* __restrict__ xout16,
    const int* __restrict__ batch, unsigned int* __restrict__ pooled, int N)
{
    __shared__ _Float16 tile[LAST ? 32 : 1][LAST ? 132 : 1];
    __shared__ int gb[LAST ? 32 : 1];
    const int tid  = threadIdx.x;
    const int lane = tid & 63;
    const int wid  = tid >> 6;           // 0..3
    const int l15  = lane & 15;
    const int lg   = lane >> 4;          // 0..3
    const int ch   = wid & 1;            // col half
    const int rg   = wid >> 1;           // row group
    const int row0 = blockIdx.x * 32 + rg * 16;
    const int blk0 = blockIdx.x * 32;

    f32x4 acc[4];
    #pragma unroll
    for (int nt = 0; nt < 4; ++nt) { f32x4 z = {0.f, 0.f, 0.f, 0.f}; acc[nt] = z; }

    int rc = row0 + l15; if (rc > N - 1) rc = N - 1;

    #pragma unroll
    for (int p = 0; p < 2; ++p) {
        const _Float16* A = p ? xin16 : agg16;
        const _Float16* a = A + (size_t)rc * 128 + lg * 8;
        const unsigned short* wh0 = Wfh + p * 16384 + (size_t)(ch * 64 + l15) * 8 + lg * 1024;
        const unsigned short* wl0 = Wfl + p * 16384 + (size_t)(ch * 64 + l15) * 8 + lg * 1024;
        #pragma unroll
        for (int ks = 0; ks < 4; ++ks) {
            h8 av = *reinterpret_cast<const h8*>(a + ks * 32);
            ushort8 hh, ll;
            #pragma unroll
            for (int j = 0; j < 8; ++j) {
                float f = (float)av[j];
                unsigned short hi = f2bh(f);
                float r = f - bh2f(hi);          // exactly representable in bf16
                hh[j] = hi;
                ll[j] = (unsigned short)(__float_as_uint(r) >> 16);
            }
            bf16x8 ah = __builtin_bit_cast(bf16x8, hh);
            bf16x8 al = __builtin_bit_cast(bf16x8, ll);
            const unsigned short* whk = wh0 + ks * 4096;
            const unsigned short* wlk = wl0 + ks * 4096;
            #pragma unroll
            for (int nt = 0; nt < 4; ++nt) {
                bf16x8 bh = *reinterpret_cast<const bf16x8*>(whk + nt * 128);
                bf16x8 bl = *reinterpret_cast<const bf16x8*>(wlk + nt * 128);
                acc[nt] = __builtin_amdgcn_mfma_f32_16x16x32_bf16(ah, bh, acc[nt], 0, 0, 0);
                acc[nt] = __builtin_amdgcn_mfma_f32_16x16x32_bf16(al, bh, acc[nt], 0, 0, 0);
                acc[nt] = __builtin_amdgcn_mfma_f32_16x16x32_bf16(ah, bl, acc[nt], 0, 0, 0);
            }
        }
    }

    #pragma unroll
    for (int nt = 0; nt < 4; ++nt) {
        int colb = ch * 64 + nt * 16 + l15;
        float bv = bias[colb];
        #pragma unroll
        for (int rr = 0; rr < 4; ++rr) {
            int row = row0 + lg * 4 + rr;
            float o = fmaxf(acc[nt][rr] + bv, 0.f);
            if (LAST) {
                tile[rg * 16 + lg * 4 + rr][colb] = (_Float16)o;
            } else if (row < N) {
                xout16[(size_t)row * 128 + colb] = (_Float16)o;
            }
        }
    }

    if (LAST) {
        if (tid < 32) gb[tid] = (blk0 + tid < N) ? batch[blk0 + tid] : -1;
        __syncthreads();
        // 256 threads = 2 row-halves x 128 cols; boundary-aware column max.
        int c  = tid & 127;
        int r0 = (tid >> 7) * 16;
        int g = -1;
        float m = 0.f;
        for (int r = r0; r < r0 + 16; ++r) {
            if (blk0 + r >= N) break;
            int bg = gb[r];
            if (bg != g) {
                if (g >= 0) atomicMax(&pooled[g * 128 + c], __float_as_uint(m));
                m = 0.f; g = bg;
            }
            m = fmaxf(m, (float)tile[r][c]);
        }
        if (g >= 0) atomicMax(&pooled[g * 128 + c], __float_as_uint(m));
    }
}

// ---------------- head ----------------

__global__ __launch_bounds__(256) void head_kernel(
    const float* __restrict__ pooled,
    const float* __restrict__ linW, const float* __restrict__ linb,
    const float* __restrict__ outW, const float* __restrict__ outb,
    float* __restrict__ out)
{
    __shared__ float pl[128];
    __shared__ float hrow[256];
    int g = blockIdx.x, t = threadIdx.x;
    if (t < 128) pl[t] = pooled[g * 128 + t];
    __syncthreads();
    float acc = linb[t];
    for (int k = 0; k < 128; ++k) acc += pl[k] * linW[k * 256 + t];
    hrow[t] = acc;
    __syncthreads();
    if (t < 10) {
        float o = outb[t];
        for (int k = 0; k < 256; ++k) o += hrow[k] * outW[k * 10 + t];
        out[g * 10 + t] = o;
    }
}

// ---------------- launch ----------------

static inline size_t align_up(size_t v, size_t a) { return (v + a - 1) & ~(a - 1); }

extern "C" void kernel_launch(void* const* d_in, const int* in_sizes, int n_in,
                              void* d_out, int out_size, void* d_ws, size_t ws_size,
                              hipStream_t stream) {
    const float* x      = (const float*)d_in[0];
    const int*   ei     = (const int*)d_in[1];
    const int*   batch  = (const int*)d_in[2];
    const float* WsSelf = (const float*)d_in[3];
    const float* WsNei  = (const float*)d_in[4];
    const float* bsAll  = (const float*)d_in[5];
    const float* linW   = (const float*)d_in[6];
    const float* linb   = (const float*)d_in[7];
    const float* outW   = (const float*)d_in[8];
    const float* outb   = (const float*)d_in[9];

    const int N = in_sizes[0] / 128;
    const int E = in_sizes[1] / 2;
    const int L = in_sizes[3] / (128 * 128);
    const int* src = ei;
    const int* dst = ei + E;
    const int nb2 = (N + 63) / 64;     // 64-node buckets (<=1024 assumed)

    // workspace carve
    char* w = (char*)d_ws;
    int* cnt       = (int*)w;  w += align_up((size_t)N * 4, 256);
    int* row_start = (int*)w;  w += align_up((size_t)(N + 1) * 4, 256);
    int* bcur      = (int*)w;  w += align_up((size_t)nb2 * 4, 256);
    int* bsum      = (int*)w;  w += align_up(256 * 4, 256);
    unsigned int* pk = (unsigned int*)w; w += align_up((size_t)E * 4, 256);
    int* col       = (int*)w;  w += align_up((size_t)E * 4, 256);
    _Float16* agg16 = (_Float16*)w; w += align_up((size_t)N * 128 * 2, 256);
    _Float16* x16in = (_Float16*)w; w += align_up((size_t)N * 128 * 2, 256);
    _Float16* xa16  = (_Float16*)w; w += align_up((size_t)N * 128 * 2, 256);
    _Float16* xb16  = (_Float16*)w; w += align_up((size_t)N * 128 * 2, 256);
    float* pooled  = (float*)w; w += align_up((size_t)64 * 128 * 4, 256);
    unsigned short* Wfh = (unsigned short*)w; w += align_up((size_t)L * 2 * 16384 * 2, 256);
    unsigned short* Wfl = (unsigned short*)w; w += align_up((size_t)L * 2 * 16384 * 2, 256);
    (void)ws_size;

    cvt16_kernel<<<(N * 16 + 255) / 256, 256, 0, stream>>>(x, x16in, N * 16, cnt, N);

    const int wtotal = L * 2 * 128 * 128;
    wprep_kernel<<<(wtotal + 255) / 256, 256, 0, stream>>>(WsNei, WsSelf, wtotal, Wfh, Wfl);

    const int nb = (N + 255) / 256;
    hist_kernel<<<(E + 255) / 256, 256, 0, stream>>>(dst, E, cnt);
    bsum_kernel<<<nb, 256, 0, stream>>>(cnt, N, bsum);
    scan_apply_kernel<<<nb, 256, 0, stream>>>(cnt, N, bsum, nb, row_start, bcur,
                                              (unsigned int*)pooled);
    partA_kernel<<<(E + EPB - 1) / EPB, 256, 0, stream>>>(src, dst, E, nb2, bcur, pk);
    partB_kernel<<<nb2, 256, 0, stream>>>(pk, row_start, N, E, col);

    const _Float16* xin16 = x16in;
    _Float16* bufs[2] = { xa16, xb16 };
    for (int l = 0; l < L; ++l) {
        agg_kernel<<<(N * 32 + 255) / 256, 256, 0, stream>>>(xin16, row_start, col, agg16, N);
        const unsigned short* wfh = Wfh + (size_t)l * 2 * 16384;
        const unsigned short* wfl = Wfl + (size_t)l * 2 * 16384;
        const float* bias = bsAll + (size_t)l * 128;
        if (l == L - 1) {
            layer_mfma<true><<<(N + 31) / 32, 256, 0, stream>>>(
                agg16, xin16, wfh, wfl, bias, nullptr, batch, (unsigned int*)pooled, N);
        } else {
            layer_mfma<false><<<(N + 31) / 32, 256, 0, stream>>>(
                agg16, xin16, wfh, wfl, bias, bufs[l & 1], batch, (unsigned int*)pooled, N);
            xin16 = bufs[l & 1];
        }
    }

    head_kernel<<<64, 256, 0, stream>>>(pooled, linW, linb, outW, outb, (float*)d_out);
}

// Round 15
// 260.958 us; speedup vs baseline: 1.2469x; 1.0098x over previous
//
#include <hip/hip_runtime.h>
#include <float.h>

typedef __bf16 bf16x8 __attribute__((ext_vector_type(8)));
typedef float f32x4 __attribute__((ext_vector_type(4)));
typedef unsigned short ushort8 __attribute__((ext_vector_type(8)));
typedef _Float16 h8 __attribute__((ext_vector_type(8)));
typedef _Float16 h4 __attribute__((ext_vector_type(4)));

__device__ inline unsigned short f2bh(float f) {
    unsigned int u = __float_as_uint(f);
    return (unsigned short)((u + 0x7FFFu + ((u >> 16) & 1u)) >> 16);
}
__device__ inline float bh2f(unsigned short h) {
    return __uint_as_float((unsigned int)h << 16);
}
__device__ inline h4 h4max(h4 a, h4 b) {
    h4 r;
    r[0] = a[0] > b[0] ? a[0] : b[0];
    r[1] = a[1] > b[1] ? a[1] : b[1];
    r[2] = a[2] > b[2] ? a[2] : b[2];
    r[3] = a[3] > b[3] ? a[3] : b[3];
    return r;
}

// ---------------- fp32 -> fp16 convert (+ zero cnt for the histogram) ----------------

__global__ void cvt16_kernel(const float* __restrict__ xin, _Float16* __restrict__ x16,
                             int total8, int* __restrict__ cnt, int N) {
    int i = blockIdx.x * blockDim.x + threadIdx.x;
    if (i < N) cnt[i] = 0;
    if (i >= total8) return;
    const float4* p = reinterpret_cast<const float4*>(xin + (size_t)i * 8);
    float4 a = p[0], b = p[1];
    h8 o;
    o[0] = (_Float16)a.x; o[1] = (_Float16)a.y; o[2] = (_Float16)a.z; o[3] = (_Float16)a.w;
    o[4] = (_Float16)b.x; o[5] = (_Float16)b.y; o[6] = (_Float16)b.z; o[7] = (_Float16)b.w;
    *reinterpret_cast<h8*>(x16 + (size_t)i * 8) = o;
}

// ---------------- CSR build: hist + scan + counting-sort partition ----------------

__global__ void hist_kernel(const int* __restrict__ dst, int E, int* __restrict__ cnt) {
    int e = blockIdx.x * blockDim.x + threadIdx.x;
    if (e < E) atomicAdd(&cnt[dst[e]], 1);
}

__global__ __launch_bounds__(256) void bsum_kernel(const int* __restrict__ cnt, int N,
                                                   int* __restrict__ bsum) {
    __shared__ int red[256];
    int t = threadIdx.x;
    int i = blockIdx.x * 256 + t;
    red[t] = (i < N) ? cnt[i] : 0;
    __syncthreads();
    for (int off = 128; off > 0; off >>= 1) {
        if (t < off) red[t] += red[t + off];
        __syncthreads();
    }
    if (t == 0) bsum[blockIdx.x] = red[0];
}

// Each block redundantly scans the (<=256) block sums, then scans its own 256
// counts; writes row_start (incl. row_start[N]=E), bucket cursors, zeroes pooled.
__global__ __launch_bounds__(256) void scan_apply_kernel(const int* __restrict__ cnt, int N,
                                                         const int* __restrict__ bsum, int nb,
                                                         int* __restrict__ row_start,
                                                         int* __restrict__ bcur,
                                                         unsigned int* __restrict__ pooled) {
    __shared__ int sb[256];
    __shared__ int s[256];
    int t = threadIdx.x;
    if (blockIdx.x == 0)
        for (int k = t; k < 64 * 128; k += 256) pooled[k] = 0u;
    sb[t] = (t < nb) ? bsum[t] : 0;
    int i = blockIdx.x * 256 + t;
    int v = (i < N) ? cnt[i] : 0;
    s[t] = v;
    __syncthreads();
    for (int off = 1; off < 256; off <<= 1) {
        int u0 = (t >= off) ? sb[t - off] : 0;
        int u1 = (t >= off) ? s[t - off] : 0;
        __syncthreads();
        sb[t] += u0;
        s[t] += u1;
        __syncthreads();
    }
    int base = (blockIdx.x == 0) ? 0 : sb[blockIdx.x - 1];
    int excl = base + s[t] - v;
    if (i < N) {
        row_start[i] = excl;
        if ((i & 63) == 0) bcur[i >> 6] = excl;   // bucket = 64 nodes
        if (i == N - 1) row_start[N] = excl + v;  // = E
    }
}

// Pass A (counting-sort style): LDS histogram per block, one global atomicAdd
// per non-empty bucket per block, then LDS-cursor ranked packed writes.
#define EPB 1024

__global__ __launch_bounds__(256) void partA_kernel(const int* __restrict__ src,
                                                    const int* __restrict__ dst, int E,
                                                    int nbkt, int* __restrict__ bcur,
                                                    unsigned int* __restrict__ pk) {
    __shared__ int lh[1024];
    __shared__ int lbase[1024];
    int t = threadIdx.x;
    int e0 = blockIdx.x * EPB;
    int e1 = e0 + EPB; if (e1 > E) e1 = E;
    for (int b = t; b < nbkt; b += 256) lh[b] = 0;
    __syncthreads();
    for (int e = e0 + t; e < e1; e += 256)
        atomicAdd(&lh[dst[e] >> 6], 1);
    __syncthreads();
    for (int b = t; b < nbkt; b += 256) {
        int c = lh[b];
        lbase[b] = (c > 0) ? atomicAdd(&bcur[b], c) : 0;
        lh[b] = 0;
    }
    __syncthreads();
    for (int e = e0 + t; e < e1; e += 256) {
        int d = dst[e];
        int b = d >> 6;
        int r = atomicAdd(&lh[b], 1);
        pk[lbase[b] + r] = ((unsigned int)src[e] << 6) | (unsigned int)(d & 63);
    }
}

// Pass B: one block per bucket; LDS cursors rank edges within each node.
__global__ __launch_bounds__(256) void partB_kernel(const unsigned int* __restrict__ pk,
                                                    const int* __restrict__ row_start,
                                                    int N, int E, int* __restrict__ col) {
    __shared__ int lrs[64];
    __shared__ int lcur[64];
    int b = blockIdx.x;
    int base = b * 64;
    int t = threadIdx.x;
    if (t < 64) {
        int node = base + t;
        lrs[t] = (node < N) ? row_start[node] : E;
        lcur[t] = 0;
    }
    __syncthreads();
    int lo = row_start[base];
    int nxt = base + 64; if (nxt > N) nxt = N;
    int hi = row_start[nxt];
    for (int i = lo + t; i < hi; i += 256) {
        unsigned int w = pk[i];
        int dl = w & 63u;
        int s = (int)(w >> 6);
        int r = atomicAdd(&lcur[dl], 1);
        col[lrs[dl] + r] = s;
    }
}

// ---------------- max aggregation (fp16): 32 lanes/node, h4, 8-way unrolled ----------------
// 32-lane shape proven best (R10); 8 independent accumulators + clamped-index
// padding (repeat last edge; harmless under max) -> no serial remainder loop.

__global__ __launch_bounds__(256) void agg_kernel(const _Float16* __restrict__ x16,
                                                  const int* __restrict__ row_start,
                                                  const int* __restrict__ col,
                                                  _Float16* __restrict__ agg16, int N) {
    int gid = blockIdx.x * blockDim.x + threadIdx.x;
    int node = gid >> 5;
    int lane = gid & 31;
    if (node >= N) return;
    int beg = row_start[node];
    int deg = row_start[node + 1] - beg;
    if (deg == 0) {
        h4 z; z[0] = (_Float16)0.f; z[1] = (_Float16)0.f; z[2] = (_Float16)0.f; z[3] = (_Float16)0.f;
        *reinterpret_cast<h4*>(&agg16[(size_t)node * 128 + lane * 4]) = z;
        return;
    }
    const _Float16 NEG = (_Float16)(-65504.0f);
    h4 a0, a1, a2, a3, a4, a5, a6, a7;
    a0[0] = NEG; a0[1] = NEG; a0[2] = NEG; a0[3] = NEG;
    a1 = a0; a2 = a0; a3 = a0; a4 = a0; a5 = a0; a6 = a0; a7 = a0;
    int dm1 = deg - 1;
    for (int j = 0; j < deg; j += 8) {
        int j1 = j + 1 > dm1 ? dm1 : j + 1;
        int j2 = j + 2 > dm1 ? dm1 : j + 2;
        int j3 = j + 3 > dm1 ? dm1 : j + 3;
        int j4 = j + 4 > dm1 ? dm1 : j + 4;
        int j5 = j + 5 > dm1 ? dm1 : j + 5;
        int j6 = j + 6 > dm1 ? dm1 : j + 6;
        int j7 = j + 7 > dm1 ? dm1 : j + 7;
        int s0 = col[beg + j];
        int s1 = col[beg + j1];
        int s2 = col[beg + j2];
        int s3 = col[beg + j3];
        int s4 = col[beg + j4];
        int s5 = col[beg + j5];
        int s6 = col[beg + j6];
        int s7 = col[beg + j7];
        a0 = h4max(a0, *reinterpret_cast<const h4*>(&x16[(size_t)s0 * 128 + lane * 4]));
        a1 = h4max(a1, *reinterpret_cast<const h4*>(&x16[(size_t)s1 * 128 + lane * 4]));
        a2 = h4max(a2, *reinterpret_cast<const h4*>(&x16[(size_t)s2 * 128 + lane * 4]));
        a3 = h4max(a3, *reinterpret_cast<const h4*>(&x16[(size_t)s3 * 128 + lane * 4]));
        a4 = h4max(a4, *reinterpret_cast<const h4*>(&x16[(size_t)s4 * 128 + lane * 4]));
        a5 = h4max(a5, *reinterpret_cast<const h4*>(&x16[(size_t)s5 * 128 + lane * 4]));
        a6 = h4max(a6, *reinterpret_cast<const h4*>(&x16[(size_t)s6 * 128 + lane * 4]));
        a7 = h4max(a7, *reinterpret_cast<const h4*>(&x16[(size_t)s7 * 128 + lane * 4]));
    }
    a0 = h4max(h4max(h4max(a0, a1), h4max(a2, a3)),
               h4max(h4max(a4, a5), h4max(a6, a7)));
    *reinterpret_cast<h4*>(&agg16[(size_t)node * 128 + lane * 4]) = a0;
}

// ---------------- W prep: split fp32 W into bf16 hi/lo, fragment-ordered ----------------
// dest layout per layer: [phase(2)][kgroup(16)][col(128)][j(8)].

__global__ void wprep_kernel(const float* __restrict__ Wn, const float* __restrict__ Wsf,
                             int total, unsigned short* __restrict__ Wfh,
                             unsigned short* __restrict__ Wfl) {
    int idx = blockIdx.x * blockDim.x + threadIdx.x;
    if (idx >= total) return;
    int c = idx & 127;
    int k = (idx >> 7) & 127;
    int p = (idx >> 14) & 1;
    int l = idx >> 15;
    const float* W = p ? Wsf : Wn;
    float v = W[(size_t)l * 16384 + k * 128 + c];
    unsigned short hi = f2bh(v);
    unsigned short lo = f2bh(v - bh2f(hi));
    size_t d = ((((size_t)l * 2 + p) * 16 + (k >> 3)) * 128 + c) * 8 + (k & 7);
    Wfh[d] = hi;
    Wfl[d] = lo;
}

// ---------------- layer GEMM via MFMA: relu([agg|x]@[Wn;Ws] + b) ----------------
// 2 row-tiles per wave (32 rows x 64 cols): each W-fragment load feeds 2 MFMAs,
// halving per-layer W L2 traffic (400 -> 200 MB). 3125 waves (~3/SIMD).
// 3-term split-bf16 (Ah@Wh + Al@Wh + Ah@Wl); fp16 A splits exactly into bf16 hi+lo.
// LAST=true: stage output tile in LDS, fused per-graph max-pool via atomicMax.

template <bool LAST>
__global__ __launch_bounds__(256) void layer_mfma(
    const _Float16* __restrict__ agg16, const _Float16* __restrict__ xin16,
    const unsigned short* __restrict__ Wfh, const unsigned short* __restrict__ Wfl,
    const float* __restrict__ bias, _Float16* __restrict__ xout16,
    const int* __restrict__ batch, unsigned int* __restrict__ pooled, int N)
{
    __shared__ _Float16 tile[LAST ? 64 : 1][LAST ? 132 : 1];
    __shared__ int gb[LAST ? 64 : 1];
    const int tid  = threadIdx.x;
    const int lane = tid & 63;
    const int wid  = tid >> 6;           // 0..3
    const int l15  = lane & 15;
    const int lg   = lane >> 4;          // 0..3
    const int ch   = wid & 1;            // col half
    const int rg   = wid >> 1;           // row group (32 rows each)
    const int blk0 = blockIdx.x * 64;
    const int row0 = blk0 + rg * 32;

    f32x4 acc[2][4];
    #pragma unroll
    for (int rt = 0; rt < 2; ++rt)
        #pragma unroll
        for (int nt = 0; nt < 4; ++nt) { f32x4 z = {0.f, 0.f, 0.f, 0.f}; acc[rt][nt] = z; }

    int rc0 = row0 + l15;      if (rc0 > N - 1) rc0 = N - 1;
    int rc1 = row0 + 16 + l15; if (rc1 > N - 1) rc1 = N - 1;

    #pragma unroll
    for (int p = 0; p < 2; ++p) {
        const _Float16* A = p ? xin16 : agg16;
        const _Float16* a0p = A + (size_t)rc0 * 128 + lg * 8;
        const _Float16* a1p = A + (size_t)rc1 * 128 + lg * 8;
        const unsigned short* wh0 = Wfh + p * 16384 + (size_t)(ch * 64 + l15) * 8 + lg * 1024;
        const unsigned short* wl0 = Wfl + p * 16384 + (size_t)(ch * 64 + l15) * 8 + lg * 1024;
        #pragma unroll
        for (int ks = 0; ks < 4; ++ks) {
            bf16x8 ah[2], al[2];
            #pragma unroll
            for (int rt = 0; rt < 2; ++rt) {
                h8 av = *reinterpret_cast<const h8*>((rt ? a1p : a0p) + ks * 32);
                ushort8 hh, ll;
                #pragma unroll
                for (int j = 0; j < 8; ++j) {
                    float f = (float)av[j];
                    unsigned short hi = f2bh(f);
                    float r = f - bh2f(hi);          // exactly representable in bf16
                    hh[j] = hi;
                    ll[j] = (unsigned short)(__float_as_uint(r) >> 16);
                }
                ah[rt] = __builtin_bit_cast(bf16x8, hh);
                al[rt] = __builtin_bit_cast(bf16x8, ll);
            }
            const unsigned short* whk = wh0 + ks * 4096;
            const unsigned short* wlk = wl0 + ks * 4096;
            #pragma unroll
            for (int nt = 0; nt < 4; ++nt) {
                bf16x8 bh = *reinterpret_cast<const bf16x8*>(whk + nt * 128);
                bf16x8 bl = *reinterpret_cast<const bf16x8*>(wlk + nt * 128);
                acc[0][nt] = __builtin_amdgcn_mfma_f32_16x16x32_bf16(ah[0], bh, acc[0][nt], 0, 0, 0);
                acc[1][nt] = __builtin_amdgcn_mfma_f32_16x16x32_bf16(ah[1], bh, acc[1][nt], 0, 0, 0);
                acc[0][nt] = __builtin_amdgcn_mfma_f32_16x16x32_bf16(al[0], bh, acc[0][nt], 0, 0, 0);
                acc[1][nt] = __builtin_amdgcn_mfma_f32_16x16x32_bf16(al[1], bh, acc[1][nt], 0, 0, 0);
                acc[0][nt] = __builtin_amdgcn_mfma_f32_16x16x32_bf16(ah[0], bl, acc[0][nt], 0, 0, 0);
                acc[1][nt] = __builtin_amdgcn_mfma_f32_16x16x32_bf16(ah[1], bl, acc[1][nt], 0, 0, 0);
            }
        }
    }

    #pragma unroll
    for (int nt = 0; nt < 4; ++nt) {
        int colb = ch * 64 + nt * 16 + l15;
        float bv = bias[colb];
        #pragma unroll
        for (int rt = 0; rt < 2; ++rt) {
            #pragma unroll
            for (int rr = 0; rr < 4; ++rr) {
                int row = row0 + rt * 16 + lg * 4 + rr;
                float o = fmaxf(acc[rt][nt][rr] + bv, 0.f);
                if (LAST) {
                    tile[rg * 32 + rt * 16 + lg * 4 + rr][colb] = (_Float16)o;
                } else if (row < N) {
                    xout16[(size_t)row * 128 + colb] = (_Float16)o;
                }
            }
        }
    }

    if (LAST) {
        if (tid < 64) gb[tid] = (blk0 + tid < N) ? batch[blk0 + tid] : -1;
        __syncthreads();
        // 256 threads = 2 row-halves x 128 cols; boundary-aware column max.
        int c  = tid & 127;
        int r0 = (tid >> 7) * 32;
        int g = -1;
        float m = 0.f;
        for (int r = r0; r < r0 + 32; ++r) {
            if (blk0 + r >= N) break;
            int bg = gb[r];
            if (bg != g) {
                if (g >= 0) atomicMax(&pooled[g * 128 + c], __float_as_uint(m));
                m = 0.f; g = bg;
            }
            m = fmaxf(m, (float)tile[r][c]);
        }
        if (g >= 0) atomicMax(&pooled[g * 128 + c], __float_as_uint(m));
    }
}

// ---------------- head ----------------

__global__ __launch_bounds__(256) void head_kernel(
    const float* __restrict__ pooled,
    const float* __restrict__ linW, const float* __restrict__ linb,
    const float* __restrict__ outW, const float* __restrict__ outb,
    float* __restrict__ out)
{
    __shared__ float pl[128];
    __shared__ float hrow[256];
    int g = blockIdx.x, t = threadIdx.x;
    if (t < 128) pl[t] = pooled[g * 128 + t];
    __syncthreads();
    float acc = linb[t];
    for (int k = 0; k < 128; ++k) acc += pl[k] * linW[k * 256 + t];
    hrow[t] = acc;
    __syncthreads();
    if (t < 10) {
        float o = outb[t];
        for (int k = 0; k < 256; ++k) o += hrow[k] * outW[k * 10 + t];
        out[g * 10 + t] = o;
    }
}

// ---------------- launch ----------------

static inline size_t align_up(size_t v, size_t a) { return (v + a - 1) & ~(a - 1); }

extern "C" void kernel_launch(void* const* d_in, const int* in_sizes, int n_in,
                              void* d_out, int out_size, void* d_ws, size_t ws_size,
                              hipStream_t stream) {
    const float* x      = (const float*)d_in[0];
    const int*   ei     = (const int*)d_in[1];
    const int*   batch  = (const int*)d_in[2];
    const float* WsSelf = (const float*)d_in[3];
    const float* WsNei  = (const float*)d_in[4];
    const float* bsAll  = (const float*)d_in[5];
    const float* linW   = (const float*)d_in[6];
    const float* linb   = (const float*)d_in[7];
    const float* outW   = (const float*)d_in[8];
    const float* outb   = (const float*)d_in[9];

    const int N = in_sizes[0] / 128;
    const int E = in_sizes[1] / 2;
    const int L = in_sizes[3] / (128 * 128);
    const int* src = ei;
    const int* dst = ei + E;
    const int nb2 = (N + 63) / 64;     // 64-node buckets (<=1024 assumed)

    // workspace carve
    char* w = (char*)d_ws;
    int* cnt       = (int*)w;  w += align_up((size_t)N * 4, 256);
    int* row_start = (int*)w;  w += align_up((size_t)(N + 1) * 4, 256);
    int* bcur      = (int*)w;  w += align_up((size_t)nb2 * 4, 256);
    int* bsum      = (int*)w;  w += align_up(256 * 4, 256);
    unsigned int* pk = (unsigned int*)w; w += align_up((size_t)E * 4, 256);
    int* col       = (int*)w;  w += align_up((size_t)E * 4, 256);
    _Float16* agg16 = (_Float16*)w; w += align_up((size_t)N * 128 * 2, 256);
    _Float16* x16in = (_Float16*)w; w += align_up((size_t)N * 128 * 2, 256);
    _Float16* xa16  = (_Float16*)w; w += align_up((size_t)N * 128 * 2, 256);
    _Float16* xb16  = (_Float16*)w; w += align_up((size_t)N * 128 * 2, 256);
    float* pooled  = (float*)w; w += align_up((size_t)64 * 128 * 4, 256);
    unsigned short* Wfh = (unsigned short*)w; w += align_up((size_t)L * 2 * 16384 * 2, 256);
    unsigned short* Wfl = (unsigned short*)w; w += align_up((size_t)L * 2 * 16384 * 2, 256);
    (void)ws_size;

    cvt16_kernel<<<(N * 16 + 255) / 256, 256, 0, stream>>>(x, x16in, N * 16, cnt, N);

    const int wtotal = L * 2 * 128 * 128;
    wprep_kernel<<<(wtotal + 255) / 256, 256, 0, stream>>>(WsNei, WsSelf, wtotal, Wfh, Wfl);

    const int nb = (N + 255) / 256;
    hist_kernel<<<(E + 255) / 256, 256, 0, stream>>>(dst, E, cnt);
    bsum_kernel<<<nb, 256, 0, stream>>>(cnt, N, bsum);
    scan_apply_kernel<<<nb, 256, 0, stream>>>(cnt, N, bsum, nb, row_start, bcur,
                                              (unsigned int*)pooled);
    partA_kernel<<<(E + EPB - 1) / EPB, 256, 0, stream>>>(src, dst, E, nb2, bcur, pk);
    partB_kernel<<<nb2, 256, 0, stream>>>(pk, row_start, N, E, col);

    const _Float16* xin16 = x16in;
    _Float16* bufs[2] = { xa16, xb16 };
    for (int l = 0; l < L; ++l) {
        agg_kernel<<<(N * 32 + 255) / 256, 256, 0, stream>>>(xin16, row_start, col, agg16, N);
        const unsigned short* wfh = Wfh + (size_t)l * 2 * 16384;
        const unsigned short* wfl = Wfl + (size_t)l * 2 * 16384;
        const float* bias = bsAll + (size_t)l * 128;
        if (l == L - 1) {
            layer_mfma<true><<<(N + 63) / 64, 256, 0, stream>>>(
                agg16, xin16, wfh, wfl, bias, nullptr, batch, (unsigned int*)pooled, N);
        } else {
            layer_mfma<false><<<(N + 63) / 64, 256, 0, stream>>>(
                agg16, xin16, wfh, wfl, bias, bufs[l & 1], batch, (unsigned int*)pooled, N);
            xin16 = bufs[l & 1];
        }
    }

    head_kernel<<<64, 256, 0, stream>>>(pooled, linW, linb, outW, outb, (float*)d_out);
}